// Round 1
// baseline (19126.735 us; speedup 1.0000x reference)
//
#include <hip/hip_runtime.h>
#include <cstddef>

#define NTOTC 16384
#define HC 256
#define LC 6
#define NEDGEC 262144
#define NHEADSC 8
#define HDC 32

// ---------------- generic tiled GEMM: C = act(A(+A2) @ W^T + bias)(+R) ----------------
// A:[M,K] row-major, W:[N,K] row-major (so C = A @ W^T), bias:[N]
// ACT: 0=none, 1=SiLU, 2=GELU(exact)
template<int ACT, bool ADD_A2, bool ADD_R>
__global__ __launch_bounds__(256) void gemm_kernel(
    const float* __restrict__ A, const float* __restrict__ A2,
    const float* __restrict__ W, const float* __restrict__ bias,
    const float* __restrict__ R, float* __restrict__ C,
    int M, int N, int K)
{
    __shared__ float As[16][68];
    __shared__ float Ws[16][68];
    const int tid = threadIdx.x;
    const int tx = tid & 15, ty = tid >> 4;
    const int m0 = blockIdx.x * 64, n0 = blockIdx.y * 64;
    float acc[4][4] = {};
    for (int k0 = 0; k0 < K; k0 += 16) {
#pragma unroll
        for (int i = 0; i < 4; i++) {
            int idx = tid + i * 256;
            int ml = idx >> 4, kl = idx & 15;
            size_t ao = (size_t)(m0 + ml) * K + (size_t)(k0 + kl);
            float v = A[ao];
            if (ADD_A2) v += A2[ao];
            As[kl][ml] = v;
            Ws[kl][ml] = W[(size_t)(n0 + ml) * K + (size_t)(k0 + kl)];
        }
        __syncthreads();
#pragma unroll
        for (int kk = 0; kk < 16; kk++) {
            float4 a4 = *reinterpret_cast<const float4*>(&As[kk][ty * 4]);
            float4 b4 = *reinterpret_cast<const float4*>(&Ws[kk][tx * 4]);
            float a[4] = {a4.x, a4.y, a4.z, a4.w};
            float b[4] = {b4.x, b4.y, b4.z, b4.w};
#pragma unroll
            for (int i = 0; i < 4; i++)
#pragma unroll
                for (int j = 0; j < 4; j++)
                    acc[i][j] += a[i] * b[j];
        }
        __syncthreads();
    }
#pragma unroll
    for (int i = 0; i < 4; i++) {
        int m = m0 + ty * 4 + i;
#pragma unroll
        for (int j = 0; j < 4; j++) {
            int n = n0 + tx * 4 + j;
            float v = acc[i][j] + bias[n];
            if (ACT == 1) v = v / (1.0f + expf(-v));
            if (ACT == 2) v = 0.5f * v * (1.0f + erff(v * 0.7071067811865476f));
            if (ADD_R) v += R[(size_t)m * N + n];
            C[(size_t)m * N + n] = v;
        }
    }
}

// ---------------- phi_e first GEMM with on-the-fly ef = [h[row], h[col], dist] ----------------
// W:[256,513] row-major. C (chunk-local [CH,256]) = SiLU(ef @ W^T + bias)
__global__ __launch_bounds__(256) void edge_gemm1_kernel(
    const float* __restrict__ hX, const int* __restrict__ rowi, const int* __restrict__ coli,
    const float* __restrict__ distv, const float* __restrict__ W, const float* __restrict__ bias,
    float* __restrict__ C)
{
    __shared__ float As[16][68];
    __shared__ float Ws[16][68];
    __shared__ int rI[64], cI[64];
    __shared__ float dS[64];
    const int tid = threadIdx.x;
    const int m0 = blockIdx.x * 64;   // chunk-local edge base
    const int n0 = blockIdx.y * 64;
    if (tid < 64) {
        rI[tid] = rowi[m0 + tid];
        cI[tid] = coli[m0 + tid];
        dS[tid] = distv[m0 + tid];
    }
    __syncthreads();
    const int tx = tid & 15, ty = tid >> 4;
    float acc[4][4] = {};
    for (int k0 = 0; k0 < 512; k0 += 16) {
#pragma unroll
        for (int i = 0; i < 4; i++) {
            int idx = tid + i * 256;
            int ml = idx >> 4, kl = idx & 15;
            int k = k0 + kl;
            float av;
            if (k < 256) av = hX[(size_t)rI[ml] * HC + k];
            else         av = hX[(size_t)cI[ml] * HC + (k - 256)];
            As[kl][ml] = av;
            Ws[kl][ml] = W[(size_t)(n0 + ml) * 513 + k];
        }
        __syncthreads();
#pragma unroll
        for (int kk = 0; kk < 16; kk++) {
            float4 a4 = *reinterpret_cast<const float4*>(&As[kk][ty * 4]);
            float4 b4 = *reinterpret_cast<const float4*>(&Ws[kk][tx * 4]);
            float a[4] = {a4.x, a4.y, a4.z, a4.w};
            float b[4] = {b4.x, b4.y, b4.z, b4.w};
#pragma unroll
            for (int i = 0; i < 4; i++)
#pragma unroll
                for (int j = 0; j < 4; j++)
                    acc[i][j] += a[i] * b[j];
        }
        __syncthreads();
    }
#pragma unroll
    for (int i = 0; i < 4; i++) {
        int ml = ty * 4 + i;
        float dv = dS[ml];
        int m = m0 + ml;
#pragma unroll
        for (int j = 0; j < 4; j++) {
            int n = n0 + tx * 4 + j;
            float v = acc[i][j] + dv * W[(size_t)n * 513 + 512] + bias[n];
            v = v / (1.0f + expf(-v));   // SiLU
            C[(size_t)m * HC + n] = v;
        }
    }
}

// ---------------- LayerNorm over H=256; 4 rows/block (one wave each) ----------------
template<bool RES>
__global__ __launch_bounds__(256) void ln_kernel(
    const float* __restrict__ X, const float* __restrict__ Rin,
    const float* __restrict__ g, const float* __restrict__ b,
    float* __restrict__ Y)
{
    const int wave = threadIdx.x >> 6, lane = threadIdx.x & 63;
    const int row = blockIdx.x * 4 + wave;
    const float* x = X + (size_t)row * HC;
    float v[4];
#pragma unroll
    for (int i = 0; i < 4; i++) {
        int c = lane + i * 64;
        v[i] = x[c];
        if (RES) v[i] += Rin[(size_t)row * HC + c];
    }
    float s = v[0] + v[1] + v[2] + v[3];
#pragma unroll
    for (int o = 32; o > 0; o >>= 1) s += __shfl_xor(s, o);
    float mean = s * (1.0f / HC);
    float q = 0.0f;
#pragma unroll
    for (int i = 0; i < 4; i++) { float d = v[i] - mean; q += d * d; }
#pragma unroll
    for (int o = 32; o > 0; o >>= 1) q += __shfl_xor(q, o);
    float inv = 1.0f / sqrtf(q * (1.0f / HC) + 1e-5f);
    float* y = Y + (size_t)row * HC;
#pragma unroll
    for (int i = 0; i < 4; i++) {
        int c = lane + i * 64;
        y[c] = (v[i] - mean) * inv * g[c] + b[c];
    }
}

// ---------------- h_msg scatter: hmsg[col[e]] += m[e] ----------------
__global__ __launch_bounds__(256) void scatter_add_kernel(
    const float* __restrict__ m, const int* __restrict__ coli, float* __restrict__ hmsg)
{
    const int e = blockIdx.x;
    const int j = threadIdx.x;
    atomicAdd(&hmsg[(size_t)coli[e] * HC + j], m[(size_t)e * HC + j]);
}

// ---------------- coeff = tanh(t2 . w2 + b2); pos_upd[col] += rel*coeff ----------------
__global__ __launch_bounds__(256) void coeff_pos_kernel(
    const float* __restrict__ t2, const float* __restrict__ w2, const float* __restrict__ b2,
    const float* __restrict__ relv, const int* __restrict__ coli, float* __restrict__ posupd)
{
    const int wave = threadIdx.x >> 6, lane = threadIdx.x & 63;
    const int e = blockIdx.x * 4 + wave;
    const float* t = t2 + (size_t)e * HC;
    float s = 0.0f;
#pragma unroll
    for (int i = 0; i < 4; i++) { int c = lane + i * 64; s += t[c] * w2[c]; }
#pragma unroll
    for (int o = 32; o > 0; o >>= 1) s += __shfl_xor(s, o);
    if (lane == 0) {
        float cf = tanhf(s + b2[0]);
        int cn = coli[e];
        atomicAdd(&posupd[(size_t)cn * 3 + 0], relv[(size_t)e * 3 + 0] * cf);
        atomicAdd(&posupd[(size_t)cn * 3 + 1], relv[(size_t)e * 3 + 1] * cf);
        atomicAdd(&posupd[(size_t)cn * 3 + 2], relv[(size_t)e * 3 + 2] * cf);
    }
}

// ---------------- rel / dist precompute ----------------
__global__ __launch_bounds__(256) void rel_dist_kernel(
    const float* __restrict__ cur, const int* __restrict__ rowi, const int* __restrict__ coli,
    float* __restrict__ rel, float* __restrict__ dist)
{
    const int e = blockIdx.x * 256 + threadIdx.x;
    int r = rowi[e], c = coli[e];
    float rx = cur[(size_t)r * 3 + 0] - cur[(size_t)c * 3 + 0];
    float ry = cur[(size_t)r * 3 + 1] - cur[(size_t)c * 3 + 1];
    float rz = cur[(size_t)r * 3 + 2] - cur[(size_t)c * 3 + 2];
    rel[(size_t)e * 3 + 0] = rx;
    rel[(size_t)e * 3 + 1] = ry;
    rel[(size_t)e * 3 + 2] = rz;
    float dx = rx + 1e-8f, dy = ry + 1e-8f, dz = rz + 1e-8f;  // reference adds eps per component
    dist[e] = sqrtf(dx * dx + dy * dy + dz * dz);
}

// ---------------- cur += ps[l] * pos_upd ----------------
__global__ __launch_bounds__(256) void cur_update_kernel(
    float* __restrict__ cur, const float* __restrict__ posupd, const float* __restrict__ ps, int l)
{
    const int i = blockIdx.x * 256 + threadIdx.x;
    cur[i] += ps[l] * posupd[i];
}

// ---------------- attention: one block per (graph, head), 64 threads ----------------
__global__ __launch_bounds__(64) void attn_kernel(
    const float* __restrict__ qkv, float* __restrict__ o)
{
    __shared__ float kS[64][33];
    __shared__ float vS[64][33];
    __shared__ float sS[64][65];
    const int g = blockIdx.x, hh = blockIdx.y;
    const int qi = threadIdx.x;
    const float* base = qkv + (size_t)(g * 64) * 768 + hh * HDC;
    float qreg[HDC];
#pragma unroll
    for (int d = 0; d < HDC; d++) qreg[d] = base[(size_t)qi * 768 + d];
#pragma unroll
    for (int d = 0; d < HDC; d++) kS[qi][d] = base[(size_t)qi * 768 + 256 + d];
#pragma unroll
    for (int d = 0; d < HDC; d++) vS[qi][d] = base[(size_t)qi * 768 + 512 + d];
    __syncthreads();
    float mx = -1e30f;
    for (int kj = 0; kj < 64; kj++) {
        float s = 0.0f;
#pragma unroll
        for (int d = 0; d < HDC; d++) s += qreg[d] * kS[kj][d];
        s *= 0.17677669529663687f;  // 1/sqrt(32)
        sS[qi][kj] = s;
        mx = fmaxf(mx, s);
    }
    float sum = 0.0f;
    for (int kj = 0; kj < 64; kj++) {
        float p = expf(sS[qi][kj] - mx);
        sS[qi][kj] = p;
        sum += p;
    }
    float inv = 1.0f / sum;
    float oacc[HDC] = {};
    for (int kj = 0; kj < 64; kj++) {
        float p = sS[qi][kj] * inv;
#pragma unroll
        for (int d = 0; d < HDC; d++) oacc[d] += p * vS[kj][d];
    }
    float* ob = o + (size_t)(g * 64 + qi) * HC + hh * HDC;
#pragma unroll
    for (int d = 0; d < HDC; d++) ob[d] = oacc[d];
}

extern "C" void kernel_launch(void* const* d_in, const int* in_sizes, int n_in,
                              void* d_out, int out_size, void* d_ws, size_t ws_size,
                              hipStream_t stream)
{
    const float* x    = (const float*)d_in[0];
    const float* pos  = (const float*)d_in[1];
    const int*   ei   = (const int*)d_in[2];
    // d_in[3] edge_attr unused, d_in[4] batch unused (equal-size graphs)
    const float* pe_w1 = (const float*)d_in[5];
    const float* pe_b1 = (const float*)d_in[6];
    const float* pe_w2 = (const float*)d_in[7];
    const float* pe_b2 = (const float*)d_in[8];
    const float* pe_lg = (const float*)d_in[9];
    const float* pe_lb = (const float*)d_in[10];
    const float* ph_w1 = (const float*)d_in[11];
    const float* ph_b1 = (const float*)d_in[12];
    const float* ph_w2 = (const float*)d_in[13];
    const float* ph_b2 = (const float*)d_in[14];
    const float* ph_lg = (const float*)d_in[15];
    const float* ph_lb = (const float*)d_in[16];
    const float* px_w1 = (const float*)d_in[17];
    const float* px_b1 = (const float*)d_in[18];
    const float* px_w2 = (const float*)d_in[19];
    const float* px_b2 = (const float*)d_in[20];
    const float* ain_w = (const float*)d_in[21];
    const float* ain_b = (const float*)d_in[22];
    const float* aout_w = (const float*)d_in[23];
    const float* aout_b = (const float*)d_in[24];
    const float* lnh_g = (const float*)d_in[25];
    const float* lnh_b = (const float*)d_in[26];
    const float* lna_g = (const float*)d_in[27];
    const float* lna_b = (const float*)d_in[28];
    const float* ff_w1 = (const float*)d_in[29];
    const float* ff_b1 = (const float*)d_in[30];
    const float* ff_w2 = (const float*)d_in[31];
    const float* ff_b2 = (const float*)d_in[32];
    const float* ps    = (const float*)d_in[33];

    float* ws = (float*)d_ws;
    float* h      = ws;                         // [NTOT,H]
    float* cur    = h + (size_t)NTOTC * HC;     // [NTOT,3]
    float* rel    = cur + (size_t)NTOTC * 3;    // [E,3]
    float* dist   = rel + (size_t)NEDGEC * 3;   // [E]
    float* posupd = dist + NEDGEC;              // [NTOT,3]
    float* buf1   = posupd + (size_t)NTOTC * 3; // [NTOT,H]  h_msg / phi_h out / o-proj
    float* buf2   = buf1 + (size_t)NTOTC * HC;  // [NTOT,H]  phi_h hidden / hu / o
    float* qkv    = buf2 + (size_t)NTOTC * HC;  // [NTOT,3H]
    float* ff1    = qkv + (size_t)NTOTC * 3 * HC; // [NTOT,4H]
    float* t1     = ff1 + (size_t)NTOTC * 4 * HC; // [CH,H]
    // mb = t1 + CH*H  (chunk message buffer)
    size_t fixedF = (size_t)(t1 - ws);

    // pick the largest edge-chunk that fits the workspace
    int CH = 65536;
    while (CH > 2048 && (fixedF + 2 * (size_t)CH * HC) * 4 > ws_size) CH >>= 1;
    float* mb = t1 + (size_t)CH * HC;
    const int NCH = NEDGEC / CH;

    hipMemcpyAsync(h, x, (size_t)NTOTC * HC * 4, hipMemcpyDeviceToDevice, stream);
    hipMemcpyAsync(cur, pos, (size_t)NTOTC * 3 * 4, hipMemcpyDeviceToDevice, stream);

    for (int l = 0; l < LC; l++) {
        const float* w_pe1 = pe_w1 + (size_t)l * HC * 513;
        const float* b_pe1 = pe_b1 + (size_t)l * HC;
        const float* w_pe2 = pe_w2 + (size_t)l * HC * HC;
        const float* b_pe2 = pe_b2 + (size_t)l * HC;

        rel_dist_kernel<<<NEDGEC / 256, 256, 0, stream>>>(cur, ei, ei + NEDGEC, rel, dist);
        hipMemsetAsync(buf1, 0, (size_t)NTOTC * HC * 4, stream);
        hipMemsetAsync(posupd, 0, (size_t)NTOTC * 3 * 4, stream);

        for (int c = 0; c < NCH; c++) {
            const int e0 = c * CH;
            edge_gemm1_kernel<<<dim3(CH / 64, 4), 256, 0, stream>>>(
                h, ei + e0, ei + NEDGEC + e0, dist + e0, w_pe1, b_pe1, t1);
            gemm_kernel<0, false, false><<<dim3(CH / 64, 4), 256, 0, stream>>>(
                t1, nullptr, w_pe2, b_pe2, nullptr, mb, CH, HC, HC);
            ln_kernel<false><<<CH / 4, 256, 0, stream>>>(
                mb, nullptr, pe_lg + (size_t)l * HC, pe_lb + (size_t)l * HC, mb);
            scatter_add_kernel<<<CH, 256, 0, stream>>>(mb, ei + NEDGEC + e0, buf1);
            gemm_kernel<1, false, false><<<dim3(CH / 64, 4), 256, 0, stream>>>(
                mb, nullptr, px_w1 + (size_t)l * HC * HC, px_b1 + (size_t)l * HC, nullptr, t1, CH, HC, HC);
            coeff_pos_kernel<<<CH / 4, 256, 0, stream>>>(
                t1, px_w2 + (size_t)l * HC, px_b2 + l, rel + (size_t)e0 * 3, ei + NEDGEC + e0, posupd);
        }

        // phi_h: hu = LN(silu((h+h_msg)@w1^T+b1)@w2^T+b2)
        gemm_kernel<1, true, false><<<dim3(NTOTC / 64, 4), 256, 0, stream>>>(
            h, buf1, ph_w1 + (size_t)l * HC * HC, ph_b1 + (size_t)l * HC, nullptr, buf2, NTOTC, HC, HC);
        gemm_kernel<0, false, false><<<dim3(NTOTC / 64, 4), 256, 0, stream>>>(
            buf2, nullptr, ph_w2 + (size_t)l * HC * HC, ph_b2 + (size_t)l * HC, nullptr, buf1, NTOTC, HC, HC);
        ln_kernel<false><<<NTOTC / 4, 256, 0, stream>>>(
            buf1, nullptr, ph_lg + (size_t)l * HC, ph_lb + (size_t)l * HC, buf2);  // hu in buf2
        ln_kernel<true><<<NTOTC / 4, 256, 0, stream>>>(
            buf2, h, lnh_g + (size_t)l * HC, lnh_b + (size_t)l * HC, h);  // h = LN(h+hu)
        cur_update_kernel<<<(NTOTC * 3) / 256, 256, 0, stream>>>(cur, posupd, ps, l);

        // attention
        gemm_kernel<0, false, false><<<dim3(NTOTC / 64, 12), 256, 0, stream>>>(
            h, nullptr, ain_w + (size_t)l * 3 * HC * HC, ain_b + (size_t)l * 3 * HC, nullptr, qkv, NTOTC, 3 * HC, HC);
        attn_kernel<<<dim3(NTOTC / 64, NHEADSC), 64, 0, stream>>>(qkv, buf2);  // o in buf2
        gemm_kernel<0, false, false><<<dim3(NTOTC / 64, 4), 256, 0, stream>>>(
            buf2, nullptr, aout_w + (size_t)l * HC * HC, aout_b + (size_t)l * HC, nullptr, buf1, NTOTC, HC, HC);
        ln_kernel<true><<<NTOTC / 4, 256, 0, stream>>>(
            buf1, h, lna_g + (size_t)l * HC, lna_b + (size_t)l * HC, h);  // h = LN(h+o)

        // feed-forward with residual
        gemm_kernel<2, false, false><<<dim3(NTOTC / 64, 16), 256, 0, stream>>>(
            h, nullptr, ff_w1 + (size_t)l * 4 * HC * HC, ff_b1 + (size_t)l * 4 * HC, nullptr, ff1, NTOTC, 4 * HC, HC);
        gemm_kernel<0, false, true><<<dim3(NTOTC / 64, 4), 256, 0, stream>>>(
            ff1, nullptr, ff_w2 + (size_t)l * 4 * HC * HC, ff_b2 + (size_t)l * HC, h, h, NTOTC, HC, 4 * HC);
    }

    hipMemcpyAsync(d_out, h, (size_t)NTOTC * HC * 4, hipMemcpyDeviceToDevice, stream);
    hipMemcpyAsync((float*)d_out + (size_t)NTOTC * HC, cur, (size_t)NTOTC * 3 * 4,
                   hipMemcpyDeviceToDevice, stream);
}

// Round 2
// 6929.019 us; speedup vs baseline: 2.7604x; 2.7604x over previous
//
#include <hip/hip_runtime.h>
#include <cstddef>
#include <cstdint>

#define NTOTC 16384
#define HC 256
#define LC 6
#define NEDGEC 262144
#define NHEADSC 8

typedef __attribute__((ext_vector_type(8))) short short8;
typedef __attribute__((ext_vector_type(4))) float f32x4;

__device__ __forceinline__ unsigned short f2bf(float f) {
    unsigned int u = __float_as_uint(f);
    u += 0x7fff + ((u >> 16) & 1);   // round-to-nearest-even
    return (unsigned short)(u >> 16);
}
__device__ __forceinline__ float bf2f(unsigned short s) {
    return __uint_as_float(((unsigned int)s) << 16);
}
__device__ __forceinline__ void async_copy16(const void* g, void* l) {
    __builtin_amdgcn_global_load_lds(
        (const __attribute__((address_space(1))) unsigned int*)g,
        (__attribute__((address_space(3))) unsigned int*)l, 16, 0, 0);
}

// ================= weight conversion =================
__global__ __launch_bounds__(256) void conv_bf16_kernel(
    const float* __restrict__ in, unsigned short* __restrict__ out, int n)
{
    for (int i = blockIdx.x * 256 + threadIdx.x; i < n; i += gridDim.x * 256)
        out[i] = f2bf(in[i]);
}

// phi_e_w1 [L,256,513] -> bf16 [L,256,512] + fp32 last column [L,256]
__global__ __launch_bounds__(256) void conv_pe1_kernel(
    const float* __restrict__ in, unsigned short* __restrict__ outk, float* __restrict__ wlast)
{
    int idx = blockIdx.x * 256 + threadIdx.x;
    if (idx >= LC * 256 * 513) return;
    int k = idx % 513;
    int nl = idx / 513;
    float v = in[idx];
    if (k == 512) wlast[nl] = v;
    else outk[(size_t)nl * 512 + k] = f2bf(v);
}

// ================= MFMA GEMM: C = act(A @ W^T + bias)(+R) =================
// A:[M,K] bf16 row-major, W:[N,K] bf16 row-major. 128x128 tile, BK=32, 4 waves.
// ACT: 0=none,1=SiLU,2=GELU(exact). RES adds fp32 R. WF writes fp32 Cf, WB writes bf16 Cb.
template<int ACT, bool RES, bool WF, bool WB>
__global__ __launch_bounds__(256) void mgemm_kernel(
    const unsigned short* __restrict__ A, const unsigned short* __restrict__ W,
    const float* __restrict__ bias, const float* __restrict__ R,
    float* __restrict__ Cf, unsigned short* __restrict__ Cb,
    int M, int N, int K)
{
    __shared__ unsigned short As[128 * 32];
    __shared__ unsigned short Bs[128 * 32];
    const int tid = threadIdx.x;
    const int lane = tid & 63, wave = tid >> 6;
    const int quad = lane >> 4, l16 = lane & 15;
    const int wm = (wave >> 1) * 64, wn = (wave & 1) * 64;
    const int m0 = blockIdx.x * 128, n0 = blockIdx.y * 128;
    f32x4 acc[4][4] = {};
    const int rbase = (lane >> 2);       // 0..15
    const int kk = (lane & 3) * 8;       // 0,8,16,24

    for (int k0 = 0; k0 < K; k0 += 32) {
#pragma unroll
        for (int c = 0; c < 2; c++) {
            int t = wave * 2 + c;
            int r = t * 16 + rbase;
            async_copy16(A + (size_t)(m0 + r) * K + k0 + kk, &As[t * 512 + lane * 8]);
            async_copy16(W + (size_t)(n0 + r) * K + k0 + kk, &Bs[t * 512 + lane * 8]);
        }
        __syncthreads();
        short8 af[4], bfr[4];
#pragma unroll
        for (int i = 0; i < 4; i++)
            af[i] = *(const short8*)&As[(wm + i * 16 + l16) * 32 + quad * 8];
#pragma unroll
        for (int j = 0; j < 4; j++)
            bfr[j] = *(const short8*)&Bs[(wn + j * 16 + l16) * 32 + quad * 8];
#pragma unroll
        for (int i = 0; i < 4; i++)
#pragma unroll
            for (int j = 0; j < 4; j++)
                acc[i][j] = __builtin_amdgcn_mfma_f32_16x16x32_bf16(af[i], bfr[j], acc[i][j], 0, 0, 0);
        __syncthreads();
    }
#pragma unroll
    for (int j = 0; j < 4; j++) {
        int col = n0 + wn + j * 16 + l16;
        float bi = bias[col];
#pragma unroll
        for (int i = 0; i < 4; i++) {
#pragma unroll
            for (int rg = 0; rg < 4; rg++) {
                int row = m0 + wm + i * 16 + quad * 4 + rg;
                float v = acc[i][j][rg] + bi;
                if (ACT == 1) v = v / (1.0f + expf(-v));
                if (ACT == 2) v = 0.5f * v * (1.0f + erff(v * 0.7071067811865476f));
                if (RES) v += R[(size_t)row * N + col];
                if (WF) Cf[(size_t)row * N + col] = v;
                if (WB) Cb[(size_t)row * N + col] = f2bf(v);
            }
        }
    }
}

// ============ phi_e GEMM1: SiLU(ef @ W^T + b), ef = [h[row], h[col], dist] ============
// hB: bf16 [NTOT,256]; Wk: bf16 [256,512]; wlast,bias fp32 [256]. Out bf16 [CH,256].
__global__ __launch_bounds__(256) void edge_mgemm1_kernel(
    const unsigned short* __restrict__ hB, const int* __restrict__ rowi, const int* __restrict__ coli,
    const float* __restrict__ distv, const unsigned short* __restrict__ Wk,
    const float* __restrict__ wlast, const float* __restrict__ bias,
    unsigned short* __restrict__ Cb)
{
    __shared__ unsigned short As[128 * 32];
    __shared__ unsigned short Bs[128 * 32];
    __shared__ int idxS[2][128];
    const int tid = threadIdx.x;
    const int lane = tid & 63, wave = tid >> 6;
    const int quad = lane >> 4, l16 = lane & 15;
    const int wm = (wave >> 1) * 64, wn = (wave & 1) * 64;
    const int m0 = blockIdx.x * 128, n0 = blockIdx.y * 128;
    if (tid < 128) {
        idxS[0][tid] = rowi[m0 + tid];
        idxS[1][tid] = coli[m0 + tid];
    }
    __syncthreads();
    f32x4 acc[4][4] = {};
    const int rbase = (lane >> 2);
    const int kk = (lane & 3) * 8;

    for (int k0 = 0; k0 < 512; k0 += 32) {
        const int half = k0 >> 8;       // 0: h[row], 1: h[col]
        const int kb = k0 & 255;
#pragma unroll
        for (int c = 0; c < 2; c++) {
            int t = wave * 2 + c;
            int r = t * 16 + rbase;
            int node = idxS[half][r];
            async_copy16(hB + (size_t)node * HC + kb + kk, &As[t * 512 + lane * 8]);
            async_copy16(Wk + (size_t)(n0 + r) * 512 + k0 + kk, &Bs[t * 512 + lane * 8]);
        }
        __syncthreads();
        short8 af[4], bfr[4];
#pragma unroll
        for (int i = 0; i < 4; i++)
            af[i] = *(const short8*)&As[(wm + i * 16 + l16) * 32 + quad * 8];
#pragma unroll
        for (int j = 0; j < 4; j++)
            bfr[j] = *(const short8*)&Bs[(wn + j * 16 + l16) * 32 + quad * 8];
#pragma unroll
        for (int i = 0; i < 4; i++)
#pragma unroll
            for (int j = 0; j < 4; j++)
                acc[i][j] = __builtin_amdgcn_mfma_f32_16x16x32_bf16(af[i], bfr[j], acc[i][j], 0, 0, 0);
        __syncthreads();
    }
#pragma unroll
    for (int j = 0; j < 4; j++) {
        int col = n0 + wn + j * 16 + l16;
        float bi = bias[col];
        float wl = wlast[col];
#pragma unroll
        for (int i = 0; i < 4; i++) {
#pragma unroll
            for (int rg = 0; rg < 4; rg++) {
                int row = m0 + wm + i * 16 + quad * 4 + rg;
                float v = acc[i][j][rg] + distv[row] * wl + bi;
                v = v / (1.0f + expf(-v));   // SiLU
                Cb[(size_t)row * HC + col] = f2bf(v);
            }
        }
    }
}

// ================= LayerNorm (fp32 input) =================
// Y = LN(X (+R)) * g + b ; writes fp32 Yf (always) and optionally bf16 Yb
template<bool RES, bool WB>
__global__ __launch_bounds__(256) void ln_f_kernel(
    const float* __restrict__ X, const float* __restrict__ Rin,
    const float* __restrict__ g, const float* __restrict__ b,
    float* __restrict__ Yf, unsigned short* __restrict__ Yb)
{
    const int wave = threadIdx.x >> 6, lane = threadIdx.x & 63;
    const int row = blockIdx.x * 4 + wave;
    const float* x = X + (size_t)row * HC;
    float v[4];
#pragma unroll
    for (int i = 0; i < 4; i++) {
        int c = lane + i * 64;
        v[i] = x[c];
        if (RES) v[i] += Rin[(size_t)row * HC + c];
    }
    float s = v[0] + v[1] + v[2] + v[3];
#pragma unroll
    for (int o = 32; o > 0; o >>= 1) s += __shfl_xor(s, o);
    float mean = s * (1.0f / HC);
    float q = 0.0f;
#pragma unroll
    for (int i = 0; i < 4; i++) { float d = v[i] - mean; q += d * d; }
#pragma unroll
    for (int o = 32; o > 0; o >>= 1) q += __shfl_xor(q, o);
    float inv = 1.0f / sqrtf(q * (1.0f / HC) + 1e-5f);
#pragma unroll
    for (int i = 0; i < 4; i++) {
        int c = lane + i * 64;
        float y = (v[i] - mean) * inv * g[c] + b[c];
        Yf[(size_t)row * HC + c] = y;
        if (WB) Yb[(size_t)row * HC + c] = f2bf(y);
    }
}

// LayerNorm in-place on bf16 buffer (edge messages)
__global__ __launch_bounds__(256) void ln_b_kernel(
    unsigned short* __restrict__ X, const float* __restrict__ g, const float* __restrict__ b)
{
    const int wave = threadIdx.x >> 6, lane = threadIdx.x & 63;
    const int row = blockIdx.x * 4 + wave;
    unsigned short* x = X + (size_t)row * HC;
    float v[4];
#pragma unroll
    for (int i = 0; i < 4; i++) v[i] = bf2f(x[lane + i * 64]);
    float s = v[0] + v[1] + v[2] + v[3];
#pragma unroll
    for (int o = 32; o > 0; o >>= 1) s += __shfl_xor(s, o);
    float mean = s * (1.0f / HC);
    float q = 0.0f;
#pragma unroll
    for (int i = 0; i < 4; i++) { float d = v[i] - mean; q += d * d; }
#pragma unroll
    for (int o = 32; o > 0; o >>= 1) q += __shfl_xor(q, o);
    float inv = 1.0f / sqrtf(q * (1.0f / HC) + 1e-5f);
#pragma unroll
    for (int i = 0; i < 4; i++) {
        int c = lane + i * 64;
        x[c] = f2bf((v[i] - mean) * inv * g[c] + b[c]);
    }
}

// ================= scatter: hmsg[col[e]] += m[e] (bf16 msgs, fp32 accum) =================
__global__ __launch_bounds__(256) void scatter_add_kernel(
    const unsigned short* __restrict__ m, const int* __restrict__ coli, float* __restrict__ hmsg)
{
    const int e = blockIdx.x;
    const int j = threadIdx.x;
    atomicAdd(&hmsg[(size_t)coli[e] * HC + j], bf2f(m[(size_t)e * HC + j]));
}

// ================= coeff = tanh(t . w2 + b2); posupd[col] += rel*coeff =================
__global__ __launch_bounds__(256) void coeff_pos_kernel(
    const unsigned short* __restrict__ t2, const float* __restrict__ w2, const float* __restrict__ b2,
    const float* __restrict__ relv, const int* __restrict__ coli, float* __restrict__ posupd)
{
    const int wave = threadIdx.x >> 6, lane = threadIdx.x & 63;
    const int e = blockIdx.x * 4 + wave;
    const unsigned short* t = t2 + (size_t)e * HC;
    float s = 0.0f;
#pragma unroll
    for (int i = 0; i < 4; i++) { int c = lane + i * 64; s += bf2f(t[c]) * w2[c]; }
#pragma unroll
    for (int o = 32; o > 0; o >>= 1) s += __shfl_xor(s, o);
    if (lane == 0) {
        float cf = tanhf(s + b2[0]);
        int cn = coli[e];
        atomicAdd(&posupd[(size_t)cn * 3 + 0], relv[(size_t)e * 3 + 0] * cf);
        atomicAdd(&posupd[(size_t)cn * 3 + 1], relv[(size_t)e * 3 + 1] * cf);
        atomicAdd(&posupd[(size_t)cn * 3 + 2], relv[(size_t)e * 3 + 2] * cf);
    }
}

// ================= rel / dist =================
__global__ __launch_bounds__(256) void rel_dist_kernel(
    const float* __restrict__ cur, const int* __restrict__ rowi, const int* __restrict__ coli,
    float* __restrict__ rel, float* __restrict__ dist)
{
    const int e = blockIdx.x * 256 + threadIdx.x;
    int r = rowi[e], c = coli[e];
    float rx = cur[(size_t)r * 3 + 0] - cur[(size_t)c * 3 + 0];
    float ry = cur[(size_t)r * 3 + 1] - cur[(size_t)c * 3 + 1];
    float rz = cur[(size_t)r * 3 + 2] - cur[(size_t)c * 3 + 2];
    rel[(size_t)e * 3 + 0] = rx;
    rel[(size_t)e * 3 + 1] = ry;
    rel[(size_t)e * 3 + 2] = rz;
    float dx = rx + 1e-8f, dy = ry + 1e-8f, dz = rz + 1e-8f;  // ref adds eps per component
    dist[e] = sqrtf(dx * dx + dy * dy + dz * dz);
}

__global__ __launch_bounds__(256) void cur_update_kernel(
    float* __restrict__ cur, const float* __restrict__ posupd, const float* __restrict__ ps, int l)
{
    const int i = blockIdx.x * 256 + threadIdx.x;
    cur[i] += ps[l] * posupd[i];
}

// ================= pack: hs_bf = bf16(h + hmsg) =================
__global__ __launch_bounds__(256) void pack_add_kernel(
    const float* __restrict__ a, const float* __restrict__ b, unsigned short* __restrict__ o)
{
    const int i = blockIdx.x * 256 + threadIdx.x;
    o[i] = f2bf(a[i] + b[i]);
}

// ================= attention: one block per (graph, head) =================
__global__ __launch_bounds__(64) void attn_kernel(
    const unsigned short* __restrict__ qkv, unsigned short* __restrict__ o)
{
    __shared__ float kS[64][33];
    __shared__ float vS[64][33];
    const int g = blockIdx.x, hh = blockIdx.y;
    const int qi = threadIdx.x;
    const unsigned short* base = qkv + (size_t)(g * 64) * 768 + hh * 32;
    float qreg[32];
#pragma unroll
    for (int d = 0; d < 32; d++) qreg[d] = bf2f(base[(size_t)qi * 768 + d]);
#pragma unroll
    for (int d = 0; d < 32; d++) kS[qi][d] = bf2f(base[(size_t)qi * 768 + 256 + d]);
#pragma unroll
    for (int d = 0; d < 32; d++) vS[qi][d] = bf2f(base[(size_t)qi * 768 + 512 + d]);
    __syncthreads();
    float sreg[64];
    float mx = -1e30f;
    for (int kj = 0; kj < 64; kj++) {
        float s = 0.0f;
#pragma unroll
        for (int d = 0; d < 32; d++) s += qreg[d] * kS[kj][d];
        s *= 0.17677669529663687f;   // 1/sqrt(32)
        sreg[kj] = s;
        mx = fmaxf(mx, s);
    }
    float sum = 0.0f;
    for (int kj = 0; kj < 64; kj++) {
        float p = expf(sreg[kj] - mx);
        sreg[kj] = p;
        sum += p;
    }
    float inv = 1.0f / sum;
    float oacc[32] = {};
    for (int kj = 0; kj < 64; kj++) {
        float p = sreg[kj] * inv;
#pragma unroll
        for (int d = 0; d < 32; d++) oacc[d] += p * vS[kj][d];
    }
    unsigned short* ob = o + (size_t)(g * 64 + qi) * HC + hh * 32;
#pragma unroll
    for (int d = 0; d < 32; d++) ob[d] = f2bf(oacc[d]);
}

extern "C" void kernel_launch(void* const* d_in, const int* in_sizes, int n_in,
                              void* d_out, int out_size, void* d_ws, size_t ws_size,
                              hipStream_t stream)
{
    const float* x    = (const float*)d_in[0];
    const float* pos  = (const float*)d_in[1];
    const int*   ei   = (const int*)d_in[2];
    const float* pe_w1 = (const float*)d_in[5];
    const float* pe_b1 = (const float*)d_in[6];
    const float* pe_w2 = (const float*)d_in[7];
    const float* pe_b2 = (const float*)d_in[8];
    const float* pe_lg = (const float*)d_in[9];
    const float* pe_lb = (const float*)d_in[10];
    const float* ph_w1 = (const float*)d_in[11];
    const float* ph_b1 = (const float*)d_in[12];
    const float* ph_w2 = (const float*)d_in[13];
    const float* ph_b2 = (const float*)d_in[14];
    const float* ph_lg = (const float*)d_in[15];
    const float* ph_lb = (const float*)d_in[16];
    const float* px_w1 = (const float*)d_in[17];
    const float* px_b1 = (const float*)d_in[18];
    const float* px_w2 = (const float*)d_in[19];
    const float* px_b2 = (const float*)d_in[20];
    const float* ain_w = (const float*)d_in[21];
    const float* ain_b = (const float*)d_in[22];
    const float* aout_w = (const float*)d_in[23];
    const float* aout_b = (const float*)d_in[24];
    const float* lnh_g = (const float*)d_in[25];
    const float* lnh_b = (const float*)d_in[26];
    const float* lna_g = (const float*)d_in[27];
    const float* lna_b = (const float*)d_in[28];
    const float* ff_w1 = (const float*)d_in[29];
    const float* ff_b1 = (const float*)d_in[30];
    const float* ff_w2 = (const float*)d_in[31];
    const float* ff_b2 = (const float*)d_in[32];
    const float* ps    = (const float*)d_in[33];

    // ---- workspace layout (64B-aligned byte allocator) ----
    char* p = (char*)d_ws;
    auto alloc = [&](size_t bytes) { char* r = p; p += (bytes + 63) & ~(size_t)63; return r; };
    float* h      = (float*)alloc((size_t)NTOTC * HC * 4);
    unsigned short* h_bf  = (unsigned short*)alloc((size_t)NTOTC * HC * 2);
    unsigned short* hs_bf = (unsigned short*)alloc((size_t)NTOTC * HC * 2);
    unsigned short* t_bf  = (unsigned short*)alloc((size_t)NTOTC * HC * 2);
    float* cur    = (float*)alloc((size_t)NTOTC * 3 * 4);
    float* rel    = (float*)alloc((size_t)NEDGEC * 3 * 4);
    float* dist   = (float*)alloc((size_t)NEDGEC * 4);
    float* posupd = (float*)alloc((size_t)NTOTC * 3 * 4);
    float* hmsg   = (float*)alloc((size_t)NTOTC * HC * 4);
    float* bufA   = (float*)alloc((size_t)NTOTC * HC * 4);
    unsigned short* qkv_bf = (unsigned short*)alloc((size_t)NTOTC * 3 * HC * 2);
    unsigned short* o_bf   = (unsigned short*)alloc((size_t)NTOTC * HC * 2);
    unsigned short* ff1_bf = (unsigned short*)alloc((size_t)NTOTC * 4 * HC * 2);
    // converted weights (bf16)
    unsigned short* w_pe1k = (unsigned short*)alloc((size_t)LC * 256 * 512 * 2);
    float*          w_last = (float*)alloc((size_t)LC * 256 * 4);
    unsigned short* w_pe2  = (unsigned short*)alloc((size_t)LC * 256 * 256 * 2);
    unsigned short* w_ph1  = (unsigned short*)alloc((size_t)LC * 256 * 256 * 2);
    unsigned short* w_ph2  = (unsigned short*)alloc((size_t)LC * 256 * 256 * 2);
    unsigned short* w_px1  = (unsigned short*)alloc((size_t)LC * 256 * 256 * 2);
    unsigned short* w_ain  = (unsigned short*)alloc((size_t)LC * 768 * 256 * 2);
    unsigned short* w_aout = (unsigned short*)alloc((size_t)LC * 256 * 256 * 2);
    unsigned short* w_ff1  = (unsigned short*)alloc((size_t)LC * 1024 * 256 * 2);
    unsigned short* w_ff2  = (unsigned short*)alloc((size_t)LC * 256 * 1024 * 2);
    size_t fixed_bytes = (size_t)(p - (char*)d_ws);
    int CH = 131072;
    while (CH > 8192 && fixed_bytes + (size_t)CH * 1024 > ws_size) CH >>= 1;
    unsigned short* t1_bf = (unsigned short*)alloc((size_t)CH * HC * 2);
    unsigned short* m_bf  = (unsigned short*)alloc((size_t)CH * HC * 2);
    const int NCH = NEDGEC / CH;

    // ---- convert weights to bf16 (every call; graph-safe) ----
    conv_pe1_kernel<<<(LC * 256 * 513 + 255) / 256, 256, 0, stream>>>(pe_w1, w_pe1k, w_last);
    conv_bf16_kernel<<<1536, 256, 0, stream>>>(pe_w2, w_pe2, LC * 256 * 256);
    conv_bf16_kernel<<<1536, 256, 0, stream>>>(ph_w1, w_ph1, LC * 256 * 256);
    conv_bf16_kernel<<<1536, 256, 0, stream>>>(ph_w2, w_ph2, LC * 256 * 256);
    conv_bf16_kernel<<<1536, 256, 0, stream>>>(px_w1, w_px1, LC * 256 * 256);
    conv_bf16_kernel<<<4608, 256, 0, stream>>>(ain_w, w_ain, LC * 768 * 256);
    conv_bf16_kernel<<<1536, 256, 0, stream>>>(aout_w, w_aout, LC * 256 * 256);
    conv_bf16_kernel<<<6144, 256, 0, stream>>>(ff_w1, w_ff1, LC * 1024 * 256);
    conv_bf16_kernel<<<6144, 256, 0, stream>>>(ff_w2, w_ff2, LC * 256 * 1024);

    hipMemcpyAsync(h, x, (size_t)NTOTC * HC * 4, hipMemcpyDeviceToDevice, stream);
    hipMemcpyAsync(cur, pos, (size_t)NTOTC * 3 * 4, hipMemcpyDeviceToDevice, stream);
    conv_bf16_kernel<<<4096, 256, 0, stream>>>(x, h_bf, NTOTC * HC);

    for (int l = 0; l < LC; l++) {
        rel_dist_kernel<<<NEDGEC / 256, 256, 0, stream>>>(cur, ei, ei + NEDGEC, rel, dist);
        hipMemsetAsync(hmsg, 0, (size_t)NTOTC * HC * 4, stream);
        hipMemsetAsync(posupd, 0, (size_t)NTOTC * 3 * 4, stream);

        for (int c = 0; c < NCH; c++) {
            const int e0 = c * CH;
            edge_mgemm1_kernel<<<dim3(CH / 128, 2), 256, 0, stream>>>(
                h_bf, ei + e0, ei + NEDGEC + e0, dist + e0,
                w_pe1k + (size_t)l * 256 * 512, w_last + (size_t)l * 256, pe_b1 + (size_t)l * HC, t1_bf);
            mgemm_kernel<0, false, false, true><<<dim3(CH / 128, 2), 256, 0, stream>>>(
                t1_bf, w_pe2 + (size_t)l * 256 * 256, pe_b2 + (size_t)l * HC,
                nullptr, nullptr, m_bf, CH, HC, HC);
            ln_b_kernel<<<CH / 4, 256, 0, stream>>>(m_bf, pe_lg + (size_t)l * HC, pe_lb + (size_t)l * HC);
            scatter_add_kernel<<<CH, 256, 0, stream>>>(m_bf, ei + NEDGEC + e0, hmsg);
            mgemm_kernel<1, false, false, true><<<dim3(CH / 128, 2), 256, 0, stream>>>(
                m_bf, w_px1 + (size_t)l * 256 * 256, px_b1 + (size_t)l * HC,
                nullptr, nullptr, t1_bf, CH, HC, HC);
            coeff_pos_kernel<<<CH / 4, 256, 0, stream>>>(
                t1_bf, px_w2 + (size_t)l * HC, px_b2 + l, rel + (size_t)e0 * 3, ei + NEDGEC + e0, posupd);
        }

        // phi_h
        pack_add_kernel<<<NTOTC * HC / 256, 256, 0, stream>>>(h, hmsg, hs_bf);
        mgemm_kernel<1, false, false, true><<<dim3(NTOTC / 128, 2), 256, 0, stream>>>(
            hs_bf, w_ph1 + (size_t)l * 256 * 256, ph_b1 + (size_t)l * HC,
            nullptr, nullptr, t_bf, NTOTC, HC, HC);
        mgemm_kernel<0, false, true, false><<<dim3(NTOTC / 128, 2), 256, 0, stream>>>(
            t_bf, w_ph2 + (size_t)l * 256 * 256, ph_b2 + (size_t)l * HC,
            nullptr, bufA, nullptr, NTOTC, HC, HC);
        ln_f_kernel<false, false><<<NTOTC / 4, 256, 0, stream>>>(
            bufA, nullptr, ph_lg + (size_t)l * HC, ph_lb + (size_t)l * HC, bufA, nullptr);  // hu in-place
        ln_f_kernel<true, true><<<NTOTC / 4, 256, 0, stream>>>(
            bufA, h, lnh_g + (size_t)l * HC, lnh_b + (size_t)l * HC, h, h_bf);  // h = LN(h+hu)
        cur_update_kernel<<<(NTOTC * 3) / 256, 256, 0, stream>>>(cur, posupd, ps, l);

        // attention
        mgemm_kernel<0, false, false, true><<<dim3(NTOTC / 128, 6), 256, 0, stream>>>(
            h_bf, w_ain + (size_t)l * 768 * 256, ain_b + (size_t)l * 3 * HC,
            nullptr, nullptr, qkv_bf, NTOTC, 3 * HC, HC);
        attn_kernel<<<dim3(NTOTC / 64, NHEADSC), 64, 0, stream>>>(qkv_bf, o_bf);
        mgemm_kernel<0, false, true, false><<<dim3(NTOTC / 128, 2), 256, 0, stream>>>(
            o_bf, w_aout + (size_t)l * 256 * 256, aout_b + (size_t)l * HC,
            nullptr, bufA, nullptr, NTOTC, HC, HC);
        ln_f_kernel<true, true><<<NTOTC / 4, 256, 0, stream>>>(
            bufA, h, lna_g + (size_t)l * HC, lna_b + (size_t)l * HC, h, h_bf);  // h = LN(h+o)

        // feed-forward with residual (no LN after)
        mgemm_kernel<2, false, false, true><<<dim3(NTOTC / 128, 8), 256, 0, stream>>>(
            h_bf, w_ff1 + (size_t)l * 1024 * 256, ff_b1 + (size_t)l * 4 * HC,
            nullptr, nullptr, ff1_bf, NTOTC, 4 * HC, HC);
        mgemm_kernel<0, true, true, true><<<dim3(NTOTC / 128, 2), 256, 0, stream>>>(
            ff1_bf, w_ff2 + (size_t)l * 256 * 1024, ff_b2 + (size_t)l * HC,
            h, h, h_bf, NTOTC, HC, 4 * HC);
    }

    hipMemcpyAsync(d_out, h, (size_t)NTOTC * HC * 4, hipMemcpyDeviceToDevice, stream);
    hipMemcpyAsync((float*)d_out + (size_t)NTOTC * HC, cur, (size_t)NTOTC * 3 * 4,
                   hipMemcpyDeviceToDevice, stream);
}

// Round 3
// 6164.132 us; speedup vs baseline: 3.1029x; 1.1241x over previous
//
#include <hip/hip_runtime.h>
#include <cstddef>
#include <cstdint>

#define NTOTC 16384
#define HC 256
#define LC 6
#define NEDGEC 262144
#define NHEADSC 8

typedef __attribute__((ext_vector_type(8))) short short8;
typedef __attribute__((ext_vector_type(4))) float f32x4;

__device__ __forceinline__ unsigned short f2bf(float f) {
    unsigned int u = __float_as_uint(f);
    u += 0x7fff + ((u >> 16) & 1);   // round-to-nearest-even
    return (unsigned short)(u >> 16);
}
__device__ __forceinline__ float bf2f(unsigned short s) {
    return __uint_as_float(((unsigned int)s) << 16);
}
__device__ __forceinline__ void async_copy16(const void* g, void* l) {
    __builtin_amdgcn_global_load_lds(
        (const __attribute__((address_space(1))) unsigned int*)g,
        (__attribute__((address_space(3))) unsigned int*)l, 16, 0, 0);
}

// ================= weight conversion =================
__global__ __launch_bounds__(256) void conv_bf16_kernel(
    const float* __restrict__ in, unsigned short* __restrict__ out, int n)
{
    for (int i = blockIdx.x * 256 + threadIdx.x; i < n; i += gridDim.x * 256)
        out[i] = f2bf(in[i]);
}

// phi_e_w1 [L,256,513] -> bf16 [L,256,512] + fp32 last column [L,256]
__global__ __launch_bounds__(256) void conv_pe1_kernel(
    const float* __restrict__ in, unsigned short* __restrict__ outk, float* __restrict__ wlast)
{
    int idx = blockIdx.x * 256 + threadIdx.x;
    if (idx >= LC * 256 * 513) return;
    int k = idx % 513;
    int nl = idx / 513;
    float v = in[idx];
    if (k == 512) wlast[nl] = v;
    else outk[(size_t)nl * 512 + k] = f2bf(v);
}

// ================= generic MFMA GEMM: C = act(A @ W^T + bias)(+R) =================
// 128x128 tile, BK=32, 4 waves. ACT: 0=none,1=SiLU,2=GELU. RES adds fp32 R.
template<int ACT, bool RES, bool WF, bool WB>
__global__ __launch_bounds__(256) void mgemm_kernel(
    const unsigned short* __restrict__ A, const unsigned short* __restrict__ W,
    const float* __restrict__ bias, const float* __restrict__ R,
    float* __restrict__ Cf, unsigned short* __restrict__ Cb,
    int M, int N, int K)
{
    __shared__ unsigned short As[128 * 32];
    __shared__ unsigned short Bs[128 * 32];
    const int tid = threadIdx.x;
    const int lane = tid & 63, wave = tid >> 6;
    const int quad = lane >> 4, l16 = lane & 15;
    const int wm = (wave >> 1) * 64, wn = (wave & 1) * 64;
    const int m0 = blockIdx.x * 128, n0 = blockIdx.y * 128;
    f32x4 acc[4][4] = {};
    const int rbase = (lane >> 2);
    const int kk = (lane & 3) * 8;

    for (int k0 = 0; k0 < K; k0 += 32) {
#pragma unroll
        for (int c = 0; c < 2; c++) {
            int t = wave * 2 + c;
            int r = t * 16 + rbase;
            async_copy16(A + (size_t)(m0 + r) * K + k0 + kk, &As[t * 512 + lane * 8]);
            async_copy16(W + (size_t)(n0 + r) * K + k0 + kk, &Bs[t * 512 + lane * 8]);
        }
        __syncthreads();
        short8 af[4], bfr[4];
#pragma unroll
        for (int i = 0; i < 4; i++)
            af[i] = *(const short8*)&As[(wm + i * 16 + l16) * 32 + quad * 8];
#pragma unroll
        for (int j = 0; j < 4; j++)
            bfr[j] = *(const short8*)&Bs[(wn + j * 16 + l16) * 32 + quad * 8];
#pragma unroll
        for (int i = 0; i < 4; i++)
#pragma unroll
            for (int j = 0; j < 4; j++)
                acc[i][j] = __builtin_amdgcn_mfma_f32_16x16x32_bf16(af[i], bfr[j], acc[i][j], 0, 0, 0);
        __syncthreads();
    }
#pragma unroll
    for (int j = 0; j < 4; j++) {
        int col = n0 + wn + j * 16 + l16;
        float bi = bias[col];
#pragma unroll
        for (int i = 0; i < 4; i++) {
#pragma unroll
            for (int rg = 0; rg < 4; rg++) {
                int row = m0 + wm + i * 16 + quad * 4 + rg;
                float v = acc[i][j][rg] + bi;
                if (ACT == 1) v = v / (1.0f + expf(-v));
                if (ACT == 2) v = 0.5f * v * (1.0f + erff(v * 0.7071067811865476f));
                if (RES) v += R[(size_t)row * N + col];
                if (WF) Cf[(size_t)row * N + col] = v;
                if (WB) Cb[(size_t)row * N + col] = f2bf(v);
            }
        }
    }
}

// ============ phi_e GEMM1: SiLU(ef @ W^T + b), ef = [h[row], h[col], dist] ============
__global__ __launch_bounds__(256) void edge_mgemm1_kernel(
    const unsigned short* __restrict__ hB, const int* __restrict__ rowi, const int* __restrict__ coli,
    const float* __restrict__ distv, const unsigned short* __restrict__ Wk,
    const float* __restrict__ wlast, const float* __restrict__ bias,
    unsigned short* __restrict__ Cb)
{
    __shared__ unsigned short As[128 * 32];
    __shared__ unsigned short Bs[128 * 32];
    __shared__ int idxS[2][128];
    const int tid = threadIdx.x;
    const int lane = tid & 63, wave = tid >> 6;
    const int quad = lane >> 4, l16 = lane & 15;
    const int wm = (wave >> 1) * 64, wn = (wave & 1) * 64;
    const int m0 = blockIdx.x * 128, n0 = blockIdx.y * 128;
    if (tid < 128) {
        idxS[0][tid] = rowi[m0 + tid];
        idxS[1][tid] = coli[m0 + tid];
    }
    __syncthreads();
    f32x4 acc[4][4] = {};
    const int rbase = (lane >> 2);
    const int kk = (lane & 3) * 8;

    for (int k0 = 0; k0 < 512; k0 += 32) {
        const int half = k0 >> 8;
        const int kb = k0 & 255;
#pragma unroll
        for (int c = 0; c < 2; c++) {
            int t = wave * 2 + c;
            int r = t * 16 + rbase;
            int node = idxS[half][r];
            async_copy16(hB + (size_t)node * HC + kb + kk, &As[t * 512 + lane * 8]);
            async_copy16(Wk + (size_t)(n0 + r) * 512 + k0 + kk, &Bs[t * 512 + lane * 8]);
        }
        __syncthreads();
        short8 af[4], bfr[4];
#pragma unroll
        for (int i = 0; i < 4; i++)
            af[i] = *(const short8*)&As[(wm + i * 16 + l16) * 32 + quad * 8];
#pragma unroll
        for (int j = 0; j < 4; j++)
            bfr[j] = *(const short8*)&Bs[(wn + j * 16 + l16) * 32 + quad * 8];
#pragma unroll
        for (int i = 0; i < 4; i++)
#pragma unroll
            for (int j = 0; j < 4; j++)
                acc[i][j] = __builtin_amdgcn_mfma_f32_16x16x32_bf16(af[i], bfr[j], acc[i][j], 0, 0, 0);
        __syncthreads();
    }
#pragma unroll
    for (int j = 0; j < 4; j++) {
        int col = n0 + wn + j * 16 + l16;
        float bi = bias[col];
        float wl = wlast[col];
#pragma unroll
        for (int i = 0; i < 4; i++) {
#pragma unroll
            for (int rg = 0; rg < 4; rg++) {
                int row = m0 + wm + i * 16 + quad * 4 + rg;
                float v = acc[i][j][rg] + distv[row] * wl + bi;
                v = v / (1.0f + expf(-v));
                Cb[(size_t)row * HC + col] = f2bf(v);
            }
        }
    }
}

// ============ fused edge tail ============
// 128 rows x full N=256 per block; 4 waves split cols (wn = wave*64).
// EPI=0: m = LN(A@W^T + bias); write m_out (bf16); atomicAdd hmsg[col[e]] += m (fp32)
// EPI=1: t = silu(A@W^T + bias); coeff=tanh(dot(t,w2)+b2); posupd[col[e]] += rel*coeff
template<int EPI>
__global__ __launch_bounds__(256) void edge_tail_kernel(
    const unsigned short* __restrict__ A, const unsigned short* __restrict__ W,
    const float* __restrict__ bias,
    const float* __restrict__ g, const float* __restrict__ b,   // EPI0: LN g,b ; EPI1: w2, &b2
    const int* __restrict__ coli, const float* __restrict__ relv,
    float* __restrict__ hmsg, unsigned short* __restrict__ m_out,
    float* __restrict__ posupd)
{
    __shared__ unsigned short As[128 * 32];
    __shared__ unsigned short Bs[256 * 32];
    __shared__ float redS[4][128];
    __shared__ float redS2[4][128];
    __shared__ int colS[128];
    const int tid = threadIdx.x;
    const int lane = tid & 63, wave = tid >> 6;
    const int quad = lane >> 4, l16 = lane & 15;
    const int wn = wave * 64;
    const int m0 = blockIdx.x * 128;
    if (tid < 128) colS[tid] = coli[m0 + tid];
    f32x4 acc[8][4] = {};
    const int rbase = (lane >> 2);
    const int kk = (lane & 3) * 8;

    for (int k0 = 0; k0 < 256; k0 += 32) {
#pragma unroll
        for (int c = 0; c < 2; c++) {
            int t = wave * 2 + c;
            int r = t * 16 + rbase;
            async_copy16(A + (size_t)(m0 + r) * 256 + k0 + kk, &As[t * 512 + lane * 8]);
        }
#pragma unroll
        for (int c = 0; c < 4; c++) {
            int t = wave * 4 + c;
            int r = t * 16 + rbase;
            async_copy16(W + (size_t)r * 256 + k0 + kk, &Bs[t * 512 + lane * 8]);
        }
        __syncthreads();
        short8 bfr[4];
#pragma unroll
        for (int j = 0; j < 4; j++)
            bfr[j] = *(const short8*)&Bs[(wn + j * 16 + l16) * 32 + quad * 8];
#pragma unroll
        for (int i = 0; i < 8; i++) {
            short8 af = *(const short8*)&As[(i * 16 + l16) * 32 + quad * 8];
#pragma unroll
            for (int j = 0; j < 4; j++)
                acc[i][j] = __builtin_amdgcn_mfma_f32_16x16x32_bf16(af, bfr[j], acc[i][j], 0, 0, 0);
        }
        __syncthreads();
    }

    float bj[4], gj[4], bbj[4];
#pragma unroll
    for (int j = 0; j < 4; j++) {
        int col = wn + j * 16 + l16;
        bj[j] = bias[col];
        gj[j] = g[col];
        if (EPI == 0) bbj[j] = b[col];
    }

    if (EPI == 0) {
#pragma unroll
        for (int i = 0; i < 8; i++)
#pragma unroll
            for (int rg = 0; rg < 4; rg++) {
                float p = 0.0f, q = 0.0f;
#pragma unroll
                for (int j = 0; j < 4; j++) {
                    float v = acc[i][j][rg] + bj[j];
                    p += v; q += v * v;
                }
#pragma unroll
                for (int off = 1; off < 16; off <<= 1) {
                    p += __shfl_xor(p, off);
                    q += __shfl_xor(q, off);
                }
                if (l16 == 0) {
                    int rl = i * 16 + quad * 4 + rg;
                    redS[wave][rl] = p;
                    redS2[wave][rl] = q;
                }
            }
        __syncthreads();
#pragma unroll
        for (int i = 0; i < 8; i++)
#pragma unroll
            for (int rg = 0; rg < 4; rg++) {
                int rl = i * 16 + quad * 4 + rg;
                float s = redS[0][rl] + redS[1][rl] + redS[2][rl] + redS[3][rl];
                float qq = redS2[0][rl] + redS2[1][rl] + redS2[2][rl] + redS2[3][rl];
                float mean = s * (1.0f / 256.0f);
                float var = qq * (1.0f / 256.0f) - mean * mean;
                float rstd = 1.0f / sqrtf(var + 1e-5f);
                int cn = colS[rl];
                size_t orow = (size_t)(m0 + rl) * 256;
#pragma unroll
                for (int j = 0; j < 4; j++) {
                    int col = wn + j * 16 + l16;
                    float v = acc[i][j][rg] + bj[j];
                    float y = (v - mean) * rstd * gj[j] + bbj[j];
                    m_out[orow + col] = f2bf(y);
                    atomicAdd(&hmsg[(size_t)cn * 256 + col], y);
                }
            }
    } else {
#pragma unroll
        for (int i = 0; i < 8; i++)
#pragma unroll
            for (int rg = 0; rg < 4; rg++) {
                float p = 0.0f;
#pragma unroll
                for (int j = 0; j < 4; j++) {
                    float v = acc[i][j][rg] + bj[j];
                    float sl = v / (1.0f + expf(-v));
                    p += sl * gj[j];
                }
#pragma unroll
                for (int off = 1; off < 16; off <<= 1) p += __shfl_xor(p, off);
                if (l16 == 0) redS[wave][i * 16 + quad * 4 + rg] = p;
            }
        __syncthreads();
#pragma unroll
        for (int i = 0; i < 8; i++)
#pragma unroll
            for (int rg = 0; rg < 4; rg++) {
                int rl = i * 16 + quad * 4 + rg;
                if (wave == 0 && l16 < 3) {
                    float tot = redS[0][rl] + redS[1][rl] + redS[2][rl] + redS[3][rl] + b[0];
                    float cf = tanhf(tot);
                    int e = m0 + rl;
                    int cn = colS[rl];
                    atomicAdd(&posupd[(size_t)cn * 3 + l16], relv[(size_t)e * 3 + l16] * cf);
                }
            }
    }
}

// ============ fused node GEMM + LN epilogue ============
// 64 rows x N=256 per block; 4 waves split cols.
// LN2=true : hu = LN1(A@W^T+bias); h = LN2(h + hu)      (phi_h tail)
// LN2=false: h = LN1(h + A@W^T + bias)                  (attn-out tail)
// writes h (fp32) and h_bf (bf16)
template<bool LN2>
__global__ __launch_bounds__(256) void node_fused_kernel(
    const unsigned short* __restrict__ A, const unsigned short* __restrict__ W,
    const float* __restrict__ bias,
    const float* __restrict__ g1, const float* __restrict__ b1,
    const float* __restrict__ g2, const float* __restrict__ b2,
    float* __restrict__ h, unsigned short* __restrict__ h_bf)
{
    __shared__ unsigned short As[64 * 32];
    __shared__ unsigned short Bs[256 * 32];
    __shared__ float redS[4][64];
    __shared__ float redS2[4][64];
    const int tid = threadIdx.x;
    const int lane = tid & 63, wave = tid >> 6;
    const int quad = lane >> 4, l16 = lane & 15;
    const int wn = wave * 64;
    const int m0 = blockIdx.x * 64;
    f32x4 acc[4][4] = {};
    const int rbase = (lane >> 2);
    const int kk = (lane & 3) * 8;

    for (int k0 = 0; k0 < 256; k0 += 32) {
        {
            int r = wave * 16 + rbase;
            async_copy16(A + (size_t)(m0 + r) * 256 + k0 + kk, &As[wave * 512 + lane * 8]);
        }
#pragma unroll
        for (int c = 0; c < 4; c++) {
            int t = wave * 4 + c;
            int r = t * 16 + rbase;
            async_copy16(W + (size_t)r * 256 + k0 + kk, &Bs[t * 512 + lane * 8]);
        }
        __syncthreads();
        short8 bfr[4];
#pragma unroll
        for (int j = 0; j < 4; j++)
            bfr[j] = *(const short8*)&Bs[(wn + j * 16 + l16) * 32 + quad * 8];
#pragma unroll
        for (int i = 0; i < 4; i++) {
            short8 af = *(const short8*)&As[(i * 16 + l16) * 32 + quad * 8];
#pragma unroll
            for (int j = 0; j < 4; j++)
                acc[i][j] = __builtin_amdgcn_mfma_f32_16x16x32_bf16(af, bfr[j], acc[i][j], 0, 0, 0);
        }
        __syncthreads();
    }

    float bj[4], g1j[4], b1j[4], g2j[4], b2j[4];
#pragma unroll
    for (int j = 0; j < 4; j++) {
        int col = wn + j * 16 + l16;
        bj[j] = bias[col];
        g1j[j] = g1[col]; b1j[j] = b1[col];
        if (LN2) { g2j[j] = g2[col]; b2j[j] = b2[col]; }
    }

    if (!LN2) {
        // acc <- z = h + v
#pragma unroll
        for (int i = 0; i < 4; i++)
#pragma unroll
            for (int rg = 0; rg < 4; rg++) {
                int rl = i * 16 + quad * 4 + rg;
#pragma unroll
                for (int j = 0; j < 4; j++) {
                    int col = wn + j * 16 + l16;
                    acc[i][j][rg] += bj[j] + h[(size_t)(m0 + rl) * 256 + col];
                }
            }
    }
    // stats round 1 (of v for LN2, of z for !LN2)
#pragma unroll
    for (int i = 0; i < 4; i++)
#pragma unroll
        for (int rg = 0; rg < 4; rg++) {
            float p = 0.0f, q = 0.0f;
#pragma unroll
            for (int j = 0; j < 4; j++) {
                float v = acc[i][j][rg] + (LN2 ? bj[j] : 0.0f);
                p += v; q += v * v;
            }
#pragma unroll
            for (int off = 1; off < 16; off <<= 1) {
                p += __shfl_xor(p, off);
                q += __shfl_xor(q, off);
            }
            if (l16 == 0) {
                int rl = i * 16 + quad * 4 + rg;
                redS[wave][rl] = p;
                redS2[wave][rl] = q;
            }
        }
    __syncthreads();

    if (!LN2) {
#pragma unroll
        for (int i = 0; i < 4; i++)
#pragma unroll
            for (int rg = 0; rg < 4; rg++) {
                int rl = i * 16 + quad * 4 + rg;
                float s = redS[0][rl] + redS[1][rl] + redS[2][rl] + redS[3][rl];
                float qq = redS2[0][rl] + redS2[1][rl] + redS2[2][rl] + redS2[3][rl];
                float mean = s * (1.0f / 256.0f);
                float rstd = 1.0f / sqrtf(qq * (1.0f / 256.0f) - mean * mean + 1e-5f);
                size_t orow = (size_t)(m0 + rl) * 256;
#pragma unroll
                for (int j = 0; j < 4; j++) {
                    int col = wn + j * 16 + l16;
                    float y = (acc[i][j][rg] - mean) * rstd * g1j[j] + b1j[j];
                    h[orow + col] = y;
                    h_bf[orow + col] = f2bf(y);
                }
            }
    } else {
        // acc <- z = h + LN1(v)
#pragma unroll
        for (int i = 0; i < 4; i++)
#pragma unroll
            for (int rg = 0; rg < 4; rg++) {
                int rl = i * 16 + quad * 4 + rg;
                float s = redS[0][rl] + redS[1][rl] + redS[2][rl] + redS[3][rl];
                float qq = redS2[0][rl] + redS2[1][rl] + redS2[2][rl] + redS2[3][rl];
                float mean = s * (1.0f / 256.0f);
                float rstd = 1.0f / sqrtf(qq * (1.0f / 256.0f) - mean * mean + 1e-5f);
#pragma unroll
                for (int j = 0; j < 4; j++) {
                    int col = wn + j * 16 + l16;
                    float v = acc[i][j][rg] + bj[j];
                    float hu = (v - mean) * rstd * g1j[j] + b1j[j];
                    acc[i][j][rg] = hu + h[(size_t)(m0 + rl) * 256 + col];
                }
            }
        __syncthreads();   // round-1 arrays fully consumed
        // stats round 2 (of z)
#pragma unroll
        for (int i = 0; i < 4; i++)
#pragma unroll
            for (int rg = 0; rg < 4; rg++) {
                float p = 0.0f, q = 0.0f;
#pragma unroll
                for (int j = 0; j < 4; j++) {
                    float v = acc[i][j][rg];
                    p += v; q += v * v;
                }
#pragma unroll
                for (int off = 1; off < 16; off <<= 1) {
                    p += __shfl_xor(p, off);
                    q += __shfl_xor(q, off);
                }
                if (l16 == 0) {
                    int rl = i * 16 + quad * 4 + rg;
                    redS[wave][rl] = p;
                    redS2[wave][rl] = q;
                }
            }
        __syncthreads();
#pragma unroll
        for (int i = 0; i < 4; i++)
#pragma unroll
            for (int rg = 0; rg < 4; rg++) {
                int rl = i * 16 + quad * 4 + rg;
                float s = redS[0][rl] + redS[1][rl] + redS[2][rl] + redS[3][rl];
                float qq = redS2[0][rl] + redS2[1][rl] + redS2[2][rl] + redS2[3][rl];
                float mean = s * (1.0f / 256.0f);
                float rstd = 1.0f / sqrtf(qq * (1.0f / 256.0f) - mean * mean + 1e-5f);
                size_t orow = (size_t)(m0 + rl) * 256;
#pragma unroll
                for (int j = 0; j < 4; j++) {
                    int col = wn + j * 16 + l16;
                    float y = (acc[i][j][rg] - mean) * rstd * g2j[j] + b2j[j];
                    h[orow + col] = y;
                    h_bf[orow + col] = f2bf(y);
                }
            }
    }
}

// ================= rel / dist =================
__global__ __launch_bounds__(256) void rel_dist_kernel(
    const float* __restrict__ cur, const int* __restrict__ rowi, const int* __restrict__ coli,
    float* __restrict__ rel, float* __restrict__ dist)
{
    const int e = blockIdx.x * 256 + threadIdx.x;
    int r = rowi[e], c = coli[e];
    float rx = cur[(size_t)r * 3 + 0] - cur[(size_t)c * 3 + 0];
    float ry = cur[(size_t)r * 3 + 1] - cur[(size_t)c * 3 + 1];
    float rz = cur[(size_t)r * 3 + 2] - cur[(size_t)c * 3 + 2];
    rel[(size_t)e * 3 + 0] = rx;
    rel[(size_t)e * 3 + 1] = ry;
    rel[(size_t)e * 3 + 2] = rz;
    float dx = rx + 1e-8f, dy = ry + 1e-8f, dz = rz + 1e-8f;
    dist[e] = sqrtf(dx * dx + dy * dy + dz * dz);
}

__global__ __launch_bounds__(256) void cur_update_kernel(
    float* __restrict__ cur, const float* __restrict__ posupd, const float* __restrict__ ps, int l)
{
    const int i = blockIdx.x * 256 + threadIdx.x;
    cur[i] += ps[l] * posupd[i];
}

// ================= pack: hs_bf = bf16(h + hmsg) =================
__global__ __launch_bounds__(256) void pack_add_kernel(
    const float* __restrict__ a, const float* __restrict__ b, unsigned short* __restrict__ o)
{
    const int i = blockIdx.x * 256 + threadIdx.x;
    o[i] = f2bf(a[i] + b[i]);
}

// ================= attention: one block per (graph, head) =================
__global__ __launch_bounds__(64) void attn_kernel(
    const unsigned short* __restrict__ qkv, unsigned short* __restrict__ o)
{
    __shared__ float kS[64][33];
    __shared__ float vS[64][33];
    const int g = blockIdx.x, hh = blockIdx.y;
    const int qi = threadIdx.x;
    const unsigned short* base = qkv + (size_t)(g * 64) * 768 + hh * 32;
    float qreg[32];
#pragma unroll
    for (int d = 0; d < 32; d++) qreg[d] = bf2f(base[(size_t)qi * 768 + d]);
#pragma unroll
    for (int d = 0; d < 32; d++) kS[qi][d] = bf2f(base[(size_t)qi * 768 + 256 + d]);
#pragma unroll
    for (int d = 0; d < 32; d++) vS[qi][d] = bf2f(base[(size_t)qi * 768 + 512 + d]);
    __syncthreads();
    float sreg[64];
    float mx = -1e30f;
    for (int kj = 0; kj < 64; kj++) {
        float s = 0.0f;
#pragma unroll
        for (int d = 0; d < 32; d++) s += qreg[d] * kS[kj][d];
        s *= 0.17677669529663687f;
        sreg[kj] = s;
        mx = fmaxf(mx, s);
    }
    float sum = 0.0f;
    for (int kj = 0; kj < 64; kj++) {
        float p = expf(sreg[kj] - mx);
        sreg[kj] = p;
        sum += p;
    }
    float inv = 1.0f / sum;
    float oacc[32] = {};
    for (int kj = 0; kj < 64; kj++) {
        float p = sreg[kj] * inv;
#pragma unroll
        for (int d = 0; d < 32; d++) oacc[d] += p * vS[kj][d];
    }
    unsigned short* ob = o + (size_t)(g * 64 + qi) * HC + hh * 32;
#pragma unroll
    for (int d = 0; d < 32; d++) ob[d] = f2bf(oacc[d]);
}

extern "C" void kernel_launch(void* const* d_in, const int* in_sizes, int n_in,
                              void* d_out, int out_size, void* d_ws, size_t ws_size,
                              hipStream_t stream)
{
    const float* x    = (const float*)d_in[0];
    const float* pos  = (const float*)d_in[1];
    const int*   ei   = (const int*)d_in[2];
    const float* pe_w1 = (const float*)d_in[5];
    const float* pe_b1 = (const float*)d_in[6];
    const float* pe_w2 = (const float*)d_in[7];
    const float* pe_b2 = (const float*)d_in[8];
    const float* pe_lg = (const float*)d_in[9];
    const float* pe_lb = (const float*)d_in[10];
    const float* ph_w1 = (const float*)d_in[11];
    const float* ph_b1 = (const float*)d_in[12];
    const float* ph_w2 = (const float*)d_in[13];
    const float* ph_b2 = (const float*)d_in[14];
    const float* ph_lg = (const float*)d_in[15];
    const float* ph_lb = (const float*)d_in[16];
    const float* px_w1 = (const float*)d_in[17];
    const float* px_b1 = (const float*)d_in[18];
    const float* px_w2 = (const float*)d_in[19];
    const float* px_b2 = (const float*)d_in[20];
    const float* ain_w = (const float*)d_in[21];
    const float* ain_b = (const float*)d_in[22];
    const float* aout_w = (const float*)d_in[23];
    const float* aout_b = (const float*)d_in[24];
    const float* lnh_g = (const float*)d_in[25];
    const float* lnh_b = (const float*)d_in[26];
    const float* lna_g = (const float*)d_in[27];
    const float* lna_b = (const float*)d_in[28];
    const float* ff_w1 = (const float*)d_in[29];
    const float* ff_b1 = (const float*)d_in[30];
    const float* ff_w2 = (const float*)d_in[31];
    const float* ff_b2 = (const float*)d_in[32];
    const float* ps    = (const float*)d_in[33];

    char* p = (char*)d_ws;
    auto alloc = [&](size_t bytes) { char* r = p; p += (bytes + 63) & ~(size_t)63; return r; };
    float* h      = (float*)alloc((size_t)NTOTC * HC * 4);
    unsigned short* h_bf  = (unsigned short*)alloc((size_t)NTOTC * HC * 2);
    unsigned short* hs_bf = (unsigned short*)alloc((size_t)NTOTC * HC * 2);
    unsigned short* t_bf  = (unsigned short*)alloc((size_t)NTOTC * HC * 2);
    float* cur    = (float*)alloc((size_t)NTOTC * 3 * 4);
    float* rel    = (float*)alloc((size_t)NEDGEC * 3 * 4);
    float* dist   = (float*)alloc((size_t)NEDGEC * 4);
    float* posupd = (float*)alloc((size_t)NTOTC * 3 * 4);
    float* hmsg   = (float*)alloc((size_t)NTOTC * HC * 4);
    unsigned short* qkv_bf = (unsigned short*)alloc((size_t)NTOTC * 3 * HC * 2);
    unsigned short* o_bf   = (unsigned short*)alloc((size_t)NTOTC * HC * 2);
    unsigned short* ff1_bf = (unsigned short*)alloc((size_t)NTOTC * 4 * HC * 2);
    unsigned short* w_pe1k = (unsigned short*)alloc((size_t)LC * 256 * 512 * 2);
    float*          w_last = (float*)alloc((size_t)LC * 256 * 4);
    unsigned short* w_pe2  = (unsigned short*)alloc((size_t)LC * 256 * 256 * 2);
    unsigned short* w_ph1  = (unsigned short*)alloc((size_t)LC * 256 * 256 * 2);
    unsigned short* w_ph2  = (unsigned short*)alloc((size_t)LC * 256 * 256 * 2);
    unsigned short* w_px1  = (unsigned short*)alloc((size_t)LC * 256 * 256 * 2);
    unsigned short* w_ain  = (unsigned short*)alloc((size_t)LC * 768 * 256 * 2);
    unsigned short* w_aout = (unsigned short*)alloc((size_t)LC * 256 * 256 * 2);
    unsigned short* w_ff1  = (unsigned short*)alloc((size_t)LC * 1024 * 256 * 2);
    unsigned short* w_ff2  = (unsigned short*)alloc((size_t)LC * 256 * 1024 * 2);
    size_t fixed_bytes = (size_t)(p - (char*)d_ws);
    int CH = 131072;
    while (CH > 8192 && fixed_bytes + (size_t)CH * 1024 > ws_size) CH >>= 1;
    unsigned short* t1_bf = (unsigned short*)alloc((size_t)CH * HC * 2);
    unsigned short* m_bf  = (unsigned short*)alloc((size_t)CH * HC * 2);
    const int NCH = NEDGEC / CH;

    conv_pe1_kernel<<<(LC * 256 * 513 + 255) / 256, 256, 0, stream>>>(pe_w1, w_pe1k, w_last);
    conv_bf16_kernel<<<1536, 256, 0, stream>>>(pe_w2, w_pe2, LC * 256 * 256);
    conv_bf16_kernel<<<1536, 256, 0, stream>>>(ph_w1, w_ph1, LC * 256 * 256);
    conv_bf16_kernel<<<1536, 256, 0, stream>>>(ph_w2, w_ph2, LC * 256 * 256);
    conv_bf16_kernel<<<1536, 256, 0, stream>>>(px_w1, w_px1, LC * 256 * 256);
    conv_bf16_kernel<<<4608, 256, 0, stream>>>(ain_w, w_ain, LC * 768 * 256);
    conv_bf16_kernel<<<1536, 256, 0, stream>>>(aout_w, w_aout, LC * 256 * 256);
    conv_bf16_kernel<<<6144, 256, 0, stream>>>(ff_w1, w_ff1, LC * 1024 * 256);
    conv_bf16_kernel<<<6144, 256, 0, stream>>>(ff_w2, w_ff2, LC * 256 * 1024);

    hipMemcpyAsync(h, x, (size_t)NTOTC * HC * 4, hipMemcpyDeviceToDevice, stream);
    hipMemcpyAsync(cur, pos, (size_t)NTOTC * 3 * 4, hipMemcpyDeviceToDevice, stream);
    conv_bf16_kernel<<<4096, 256, 0, stream>>>(x, h_bf, NTOTC * HC);

    for (int l = 0; l < LC; l++) {
        rel_dist_kernel<<<NEDGEC / 256, 256, 0, stream>>>(cur, ei, ei + NEDGEC, rel, dist);
        hipMemsetAsync(hmsg, 0, (size_t)NTOTC * HC * 4, stream);
        hipMemsetAsync(posupd, 0, (size_t)NTOTC * 3 * 4, stream);

        for (int c = 0; c < NCH; c++) {
            const int e0 = c * CH;
            edge_mgemm1_kernel<<<dim3(CH / 128, 2), 256, 0, stream>>>(
                h_bf, ei + e0, ei + NEDGEC + e0, dist + e0,
                w_pe1k + (size_t)l * 256 * 512, w_last + (size_t)l * 256, pe_b1 + (size_t)l * HC, t1_bf);
            edge_tail_kernel<0><<<CH / 128, 256, 0, stream>>>(
                t1_bf, w_pe2 + (size_t)l * 256 * 256, pe_b2 + (size_t)l * HC,
                pe_lg + (size_t)l * HC, pe_lb + (size_t)l * HC,
                ei + NEDGEC + e0, nullptr, hmsg, m_bf, nullptr);
            edge_tail_kernel<1><<<CH / 128, 256, 0, stream>>>(
                m_bf, w_px1 + (size_t)l * 256 * 256, px_b1 + (size_t)l * HC,
                px_w2 + (size_t)l * HC, px_b2 + l,
                ei + NEDGEC + e0, rel + (size_t)e0 * 3, nullptr, nullptr, posupd);
        }

        // phi_h tail
        pack_add_kernel<<<NTOTC * HC / 256, 256, 0, stream>>>(h, hmsg, hs_bf);
        mgemm_kernel<1, false, false, true><<<dim3(NTOTC / 128, 2), 256, 0, stream>>>(
            hs_bf, w_ph1 + (size_t)l * 256 * 256, ph_b1 + (size_t)l * HC,
            nullptr, nullptr, t_bf, NTOTC, HC, HC);
        node_fused_kernel<true><<<NTOTC / 64, 256, 0, stream>>>(
            t_bf, w_ph2 + (size_t)l * 256 * 256, ph_b2 + (size_t)l * HC,
            ph_lg + (size_t)l * HC, ph_lb + (size_t)l * HC,
            lnh_g + (size_t)l * HC, lnh_b + (size_t)l * HC, h, h_bf);
        cur_update_kernel<<<(NTOTC * 3) / 256, 256, 0, stream>>>(cur, posupd, ps, l);

        // attention
        mgemm_kernel<0, false, false, true><<<dim3(NTOTC / 128, 6), 256, 0, stream>>>(
            h_bf, w_ain + (size_t)l * 768 * 256, ain_b + (size_t)l * 3 * HC,
            nullptr, nullptr, qkv_bf, NTOTC, 3 * HC, HC);
        attn_kernel<<<dim3(NTOTC / 64, NHEADSC), 64, 0, stream>>>(qkv_bf, o_bf);
        node_fused_kernel<false><<<NTOTC / 64, 256, 0, stream>>>(
            o_bf, w_aout + (size_t)l * 256 * 256, aout_b + (size_t)l * HC,
            lna_g + (size_t)l * HC, lna_b + (size_t)l * HC,
            nullptr, nullptr, h, h_bf);

        // feed-forward with residual
        mgemm_kernel<2, false, false, true><<<dim3(NTOTC / 128, 8), 256, 0, stream>>>(
            h_bf, w_ff1 + (size_t)l * 1024 * 256, ff_b1 + (size_t)l * 4 * HC,
            nullptr, nullptr, ff1_bf, NTOTC, 4 * HC, HC);
        mgemm_kernel<0, true, true, true><<<dim3(NTOTC / 128, 2), 256, 0, stream>>>(
            ff1_bf, w_ff2 + (size_t)l * 256 * 1024, ff_b2 + (size_t)l * HC,
            h, h, h_bf, NTOTC, HC, 4 * HC);
    }

    hipMemcpyAsync(d_out, h, (size_t)NTOTC * HC * 4, hipMemcpyDeviceToDevice, stream);
    hipMemcpyAsync((float*)d_out + (size_t)NTOTC * HC, cur, (size_t)NTOTC * 3 * 4,
                   hipMemcpyDeviceToDevice, stream);
}

// Round 4
// 4870.413 us; speedup vs baseline: 3.9271x; 1.2656x over previous
//
#include <hip/hip_runtime.h>
#include <cstddef>
#include <cstdint>

#define NTOTC 16384
#define HC 256
#define LC 6
#define NEDGEC 262144
#define NHEADSC 8

typedef __attribute__((ext_vector_type(8))) short short8;
typedef __attribute__((ext_vector_type(4))) float f32x4;

__device__ __forceinline__ unsigned short f2bf(float f) {
    unsigned int u = __float_as_uint(f);
    u += 0x7fff + ((u >> 16) & 1);   // round-to-nearest-even
    return (unsigned short)(u >> 16);
}
__device__ __forceinline__ float bf2f(unsigned short s) {
    return __uint_as_float(((unsigned int)s) << 16);
}
__device__ __forceinline__ void async_copy16(const void* g, void* l) {
    __builtin_amdgcn_global_load_lds(
        (const __attribute__((address_space(1))) unsigned int*)g,
        (__attribute__((address_space(3))) unsigned int*)l, 16, 0, 0);
}

// ================= weight conversion =================
__global__ __launch_bounds__(256) void conv_bf16_kernel(
    const float* __restrict__ in, unsigned short* __restrict__ out, int n)
{
    for (int i = blockIdx.x * 256 + threadIdx.x; i < n; i += gridDim.x * 256)
        out[i] = f2bf(in[i]);
}

// phi_e_w1 [L,256,513] -> bf16 [L,256,512] + fp32 last column [L,256]
__global__ __launch_bounds__(256) void conv_pe1_kernel(
    const float* __restrict__ in, unsigned short* __restrict__ outk, float* __restrict__ wlast)
{
    int idx = blockIdx.x * 256 + threadIdx.x;
    if (idx >= LC * 256 * 513) return;
    int k = idx % 513;
    int nl = idx / 513;
    float v = in[idx];
    if (k == 512) wlast[nl] = v;
    else outk[(size_t)nl * 512 + k] = f2bf(v);
}

// ================= counting sort of edges by col =================
__global__ __launch_bounds__(256) void hist_kernel(
    const int* __restrict__ col, int* __restrict__ cnt)
{
    int e = blockIdx.x * 256 + threadIdx.x;
    atomicAdd(&cnt[col[e]], 1);
}

// exclusive prefix over 16384 bins, single block of 256 threads
__global__ __launch_bounds__(256) void scan16k_kernel(
    const int* __restrict__ cnt, int* __restrict__ ptrw)
{
    __shared__ int partial[256];
    const int t = threadIdx.x;
    const int base = t * 64;
    int loc[64];
    int s = 0;
#pragma unroll
    for (int i = 0; i < 64; i++) { loc[i] = s; s += cnt[base + i]; }
    partial[t] = s;
    __syncthreads();
    if (t == 0) {
        int run = 0;
        for (int i = 0; i < 256; i++) { int tmp = partial[i]; partial[i] = run; run += tmp; }
    }
    __syncthreads();
    int off = partial[t];
#pragma unroll
    for (int i = 0; i < 64; i++) ptrw[base + i] = off + loc[i];
}

__global__ __launch_bounds__(256) void permute_kernel(
    const int* __restrict__ row, const int* __restrict__ col, int* __restrict__ ptrw,
    int* __restrict__ rowP, int* __restrict__ colP)
{
    int e = blockIdx.x * 256 + threadIdx.x;
    int c = col[e];
    int pos = atomicAdd(&ptrw[c], 1);
    rowP[pos] = row[e];
    colP[pos] = c;
}

// ================= generic MFMA GEMM: C = act(A @ W^T + bias)(+R) =================
// 128x128 tile, BK=32, 4 waves. ACT: 0=none,1=SiLU,2=GELU. RES adds fp32 R.
template<int ACT, bool RES, bool WF, bool WB>
__global__ __launch_bounds__(256) void mgemm_kernel(
    const unsigned short* __restrict__ A, const unsigned short* __restrict__ W,
    const float* __restrict__ bias, const float* __restrict__ R,
    float* __restrict__ Cf, unsigned short* __restrict__ Cb,
    int M, int N, int K)
{
    __shared__ unsigned short As[128 * 32];
    __shared__ unsigned short Bs[128 * 32];
    const int tid = threadIdx.x;
    const int lane = tid & 63, wave = tid >> 6;
    const int quad = lane >> 4, l16 = lane & 15;
    const int wm = (wave >> 1) * 64, wn = (wave & 1) * 64;
    const int m0 = blockIdx.x * 128, n0 = blockIdx.y * 128;
    f32x4 acc[4][4] = {};
    const int rbase = (lane >> 2);
    const int kk = (lane & 3) * 8;

    for (int k0 = 0; k0 < K; k0 += 32) {
#pragma unroll
        for (int c = 0; c < 2; c++) {
            int t = wave * 2 + c;
            int r = t * 16 + rbase;
            async_copy16(A + (size_t)(m0 + r) * K + k0 + kk, &As[t * 512 + lane * 8]);
            async_copy16(W + (size_t)(n0 + r) * K + k0 + kk, &Bs[t * 512 + lane * 8]);
        }
        __syncthreads();
        short8 af[4], bfr[4];
#pragma unroll
        for (int i = 0; i < 4; i++)
            af[i] = *(const short8*)&As[(wm + i * 16 + l16) * 32 + quad * 8];
#pragma unroll
        for (int j = 0; j < 4; j++)
            bfr[j] = *(const short8*)&Bs[(wn + j * 16 + l16) * 32 + quad * 8];
#pragma unroll
        for (int i = 0; i < 4; i++)
#pragma unroll
            for (int j = 0; j < 4; j++)
                acc[i][j] = __builtin_amdgcn_mfma_f32_16x16x32_bf16(af[i], bfr[j], acc[i][j], 0, 0, 0);
        __syncthreads();
    }
#pragma unroll
    for (int j = 0; j < 4; j++) {
        int col = n0 + wn + j * 16 + l16;
        float bi = bias[col];
#pragma unroll
        for (int i = 0; i < 4; i++) {
#pragma unroll
            for (int rg = 0; rg < 4; rg++) {
                int row = m0 + wm + i * 16 + quad * 4 + rg;
                float v = acc[i][j][rg] + bi;
                if (ACT == 1) v = v / (1.0f + expf(-v));
                if (ACT == 2) v = 0.5f * v * (1.0f + erff(v * 0.7071067811865476f));
                if (RES) v += R[(size_t)row * N + col];
                if (WF) Cf[(size_t)row * N + col] = v;
                if (WB) Cb[(size_t)row * N + col] = f2bf(v);
            }
        }
    }
}

// ================= FULLY FUSED edge pipeline =================
// Per block: 64 sorted edges, all 256 output cols.
// GEMM1: t1 = silu([h[row],h[col]] @ W1^T + dist*wlast + b1)   (K=512, LDS out)
// GEMM2: m = LN(t1 @ W2^T + b2)                                 (K=256, LDS out)
//   -> segmented scatter: hmsg[col] += m  (sorted cols -> few atomics)
// GEMM3: t3 = silu(m @ W3^T + b3); cf = tanh(dot(t3,w2v)+b2s)
//   -> segmented scatter: posupd[col] += rel*cf
__global__ __launch_bounds__(256) void fused_edge_kernel(
    const unsigned short* __restrict__ hB,
    const int* __restrict__ rowP, const int* __restrict__ colP,
    const float* __restrict__ distv, const float* __restrict__ relv,
    const unsigned short* __restrict__ W1, const float* __restrict__ wlast,
    const float* __restrict__ b1,
    const unsigned short* __restrict__ W2, const float* __restrict__ b2,
    const float* __restrict__ lg, const float* __restrict__ lb,
    const unsigned short* __restrict__ W3, const float* __restrict__ b3,
    const float* __restrict__ w2v, const float* __restrict__ b2s,
    float* __restrict__ hmsg, float* __restrict__ posupd)
{
    __shared__ unsigned short As[64 * 32];
    __shared__ unsigned short Bs[256 * 32];
    __shared__ unsigned short tS[64 * 264];     // padded: row stride 264 shorts
    __shared__ float redS[4][64];
    __shared__ float redS2[4][64];
    __shared__ int rowS[64], colS[64];
    __shared__ float distS[64];
    __shared__ float relS[64][3];
    __shared__ float cfS[64];

    const int tid = threadIdx.x;
    const int lane = tid & 63, wave = tid >> 6;
    const int quad = lane >> 4, l16 = lane & 15;
    const int wn = wave * 64;
    const int m0 = blockIdx.x * 64;
    const int rbase = lane >> 2;
    const int kk = (lane & 3) * 8;

    if (tid < 64) {
        rowS[tid] = rowP[m0 + tid];
        colS[tid] = colP[m0 + tid];
        distS[tid] = distv[m0 + tid];
        relS[tid][0] = relv[(size_t)(m0 + tid) * 3 + 0];
        relS[tid][1] = relv[(size_t)(m0 + tid) * 3 + 1];
        relS[tid][2] = relv[(size_t)(m0 + tid) * 3 + 2];
    }
    __syncthreads();

    f32x4 acc[4][4] = {};

    // ---- GEMM1: K=512 (gathered h) ----
    for (int k0 = 0; k0 < 512; k0 += 32) {
        const int half = k0 >> 8;
        const int kb = k0 & 255;
        {
            int r = wave * 16 + rbase;
            int node = half ? colS[r] : rowS[r];
            async_copy16(hB + (size_t)node * 256 + kb + kk, &As[wave * 512 + lane * 8]);
        }
#pragma unroll
        for (int c = 0; c < 4; c++) {
            int t = wave * 4 + c;
            int r = t * 16 + rbase;
            async_copy16(W1 + (size_t)r * 512 + k0 + kk, &Bs[t * 512 + lane * 8]);
        }
        __syncthreads();
        short8 af[4], bfr[4];
#pragma unroll
        for (int j = 0; j < 4; j++)
            bfr[j] = *(const short8*)&Bs[(wn + j * 16 + l16) * 32 + quad * 8];
#pragma unroll
        for (int i = 0; i < 4; i++)
            af[i] = *(const short8*)&As[(i * 16 + l16) * 32 + quad * 8];
#pragma unroll
        for (int i = 0; i < 4; i++)
#pragma unroll
            for (int j = 0; j < 4; j++)
                acc[i][j] = __builtin_amdgcn_mfma_f32_16x16x32_bf16(af[i], bfr[j], acc[i][j], 0, 0, 0);
        __syncthreads();
    }
    // epilogue 1: silu(acc + dist*wlast + b1) -> tS
    {
        float wlj[4], b1j[4];
#pragma unroll
        for (int j = 0; j < 4; j++) {
            int col = wn + j * 16 + l16;
            wlj[j] = wlast[col];
            b1j[j] = b1[col];
        }
#pragma unroll
        for (int i = 0; i < 4; i++)
#pragma unroll
            for (int rg = 0; rg < 4; rg++) {
                int row = i * 16 + quad * 4 + rg;
                float dv = distS[row];
#pragma unroll
                for (int j = 0; j < 4; j++) {
                    int col = wn + j * 16 + l16;
                    float v = acc[i][j][rg] + dv * wlj[j] + b1j[j];
                    v = v / (1.0f + expf(-v));
                    tS[row * 264 + col] = f2bf(v);
                }
            }
    }
    __syncthreads();

    // ---- GEMM2: K=256, A from tS ----
#pragma unroll
    for (int i = 0; i < 4; i++)
#pragma unroll
        for (int j = 0; j < 4; j++) acc[i][j] = (f32x4){0.f, 0.f, 0.f, 0.f};
    for (int k0 = 0; k0 < 256; k0 += 32) {
#pragma unroll
        for (int c = 0; c < 4; c++) {
            int t = wave * 4 + c;
            int r = t * 16 + rbase;
            async_copy16(W2 + (size_t)r * 256 + k0 + kk, &Bs[t * 512 + lane * 8]);
        }
        __syncthreads();
        short8 af[4], bfr[4];
#pragma unroll
        for (int j = 0; j < 4; j++)
            bfr[j] = *(const short8*)&Bs[(wn + j * 16 + l16) * 32 + quad * 8];
#pragma unroll
        for (int i = 0; i < 4; i++)
            af[i] = *(const short8*)&tS[(i * 16 + l16) * 264 + k0 + quad * 8];
#pragma unroll
        for (int i = 0; i < 4; i++)
#pragma unroll
            for (int j = 0; j < 4; j++)
                acc[i][j] = __builtin_amdgcn_mfma_f32_16x16x32_bf16(af[i], bfr[j], acc[i][j], 0, 0, 0);
        __syncthreads();
    }
    // epilogue 2: LN -> m -> tS (overwrite)
    {
        float b2j[4], gj[4], bbj[4];
#pragma unroll
        for (int j = 0; j < 4; j++) {
            int col = wn + j * 16 + l16;
            b2j[j] = b2[col];
            gj[j] = lg[col];
            bbj[j] = lb[col];
        }
#pragma unroll
        for (int i = 0; i < 4; i++)
#pragma unroll
            for (int rg = 0; rg < 4; rg++) {
                float p = 0.0f, q = 0.0f;
#pragma unroll
                for (int j = 0; j < 4; j++) {
                    float v = acc[i][j][rg] + b2j[j];
                    p += v; q += v * v;
                }
#pragma unroll
                for (int off = 1; off < 16; off <<= 1) {
                    p += __shfl_xor(p, off);
                    q += __shfl_xor(q, off);
                }
                if (l16 == 0) {
                    int row = i * 16 + quad * 4 + rg;
                    redS[wave][row] = p;
                    redS2[wave][row] = q;
                }
            }
        __syncthreads();
#pragma unroll
        for (int i = 0; i < 4; i++)
#pragma unroll
            for (int rg = 0; rg < 4; rg++) {
                int row = i * 16 + quad * 4 + rg;
                float s = redS[0][row] + redS[1][row] + redS[2][row] + redS[3][row];
                float qq = redS2[0][row] + redS2[1][row] + redS2[2][row] + redS2[3][row];
                float mean = s * (1.0f / 256.0f);
                float rstd = 1.0f / sqrtf(qq * (1.0f / 256.0f) - mean * mean + 1e-5f);
#pragma unroll
                for (int j = 0; j < 4; j++) {
                    int col = wn + j * 16 + l16;
                    float v = acc[i][j][rg] + b2j[j];
                    float y = (v - mean) * rstd * gj[j] + bbj[j];
                    tS[row * 264 + col] = f2bf(y);
                }
            }
    }
    __syncthreads();

    // ---- segmented scatter of m into hmsg (cols sorted; few atomics) ----
    {
        const int c = tid;   // 0..255 = hidden col
        int r = 0;
        while (r < 64) {
            int node = colS[r];
            float s = 0.0f;
            do { s += bf2f(tS[r * 264 + c]); r++; } while (r < 64 && colS[r] == node);
            atomicAdd(&hmsg[(size_t)node * 256 + c], s);
        }
    }

    // ---- GEMM3: K=256, A = m from tS ----
#pragma unroll
    for (int i = 0; i < 4; i++)
#pragma unroll
        for (int j = 0; j < 4; j++) acc[i][j] = (f32x4){0.f, 0.f, 0.f, 0.f};
    for (int k0 = 0; k0 < 256; k0 += 32) {
#pragma unroll
        for (int c = 0; c < 4; c++) {
            int t = wave * 4 + c;
            int r = t * 16 + rbase;
            async_copy16(W3 + (size_t)r * 256 + k0 + kk, &Bs[t * 512 + lane * 8]);
        }
        __syncthreads();
        short8 af[4], bfr[4];
#pragma unroll
        for (int j = 0; j < 4; j++)
            bfr[j] = *(const short8*)&Bs[(wn + j * 16 + l16) * 32 + quad * 8];
#pragma unroll
        for (int i = 0; i < 4; i++)
            af[i] = *(const short8*)&tS[(i * 16 + l16) * 264 + k0 + quad * 8];
#pragma unroll
        for (int i = 0; i < 4; i++)
#pragma unroll
            for (int j = 0; j < 4; j++)
                acc[i][j] = __builtin_amdgcn_mfma_f32_16x16x32_bf16(af[i], bfr[j], acc[i][j], 0, 0, 0);
        __syncthreads();
    }
    // epilogue 3: coeff = tanh(dot(silu(acc+b3), w2v) + b2s); posupd scatter
    {
        float b3j[4], w2j[4];
#pragma unroll
        for (int j = 0; j < 4; j++) {
            int col = wn + j * 16 + l16;
            b3j[j] = b3[col];
            w2j[j] = w2v[col];
        }
#pragma unroll
        for (int i = 0; i < 4; i++)
#pragma unroll
            for (int rg = 0; rg < 4; rg++) {
                float p = 0.0f;
#pragma unroll
                for (int j = 0; j < 4; j++) {
                    float v = acc[i][j][rg] + b3j[j];
                    p += (v / (1.0f + expf(-v))) * w2j[j];
                }
#pragma unroll
                for (int off = 1; off < 16; off <<= 1) p += __shfl_xor(p, off);
                if (l16 == 0) redS[wave][i * 16 + quad * 4 + rg] = p;
            }
        __syncthreads();
        if (tid < 64) {
            float tot = redS[0][tid] + redS[1][tid] + redS[2][tid] + redS[3][tid] + b2s[0];
            cfS[tid] = tanhf(tot);
        }
        __syncthreads();
        if (tid < 3) {
            const int comp = tid;
            int r = 0;
            while (r < 64) {
                int node = colS[r];
                float s = 0.0f;
                do { s += relS[r][comp] * cfS[r]; r++; } while (r < 64 && colS[r] == node);
                atomicAdd(&posupd[(size_t)node * 3 + comp], s);
            }
        }
    }
}

// ============ fused node GEMM + LN epilogue ============
template<bool LN2>
__global__ __launch_bounds__(256) void node_fused_kernel(
    const unsigned short* __restrict__ A, const unsigned short* __restrict__ W,
    const float* __restrict__ bias,
    const float* __restrict__ g1, const float* __restrict__ b1,
    const float* __restrict__ g2, const float* __restrict__ b2,
    float* __restrict__ h, unsigned short* __restrict__ h_bf)
{
    __shared__ unsigned short As[64 * 32];
    __shared__ unsigned short Bs[256 * 32];
    __shared__ float redS[4][64];
    __shared__ float redS2[4][64];
    const int tid = threadIdx.x;
    const int lane = tid & 63, wave = tid >> 6;
    const int quad = lane >> 4, l16 = lane & 15;
    const int wn = wave * 64;
    const int m0 = blockIdx.x * 64;
    f32x4 acc[4][4] = {};
    const int rbase = (lane >> 2);
    const int kk = (lane & 3) * 8;

    for (int k0 = 0; k0 < 256; k0 += 32) {
        {
            int r = wave * 16 + rbase;
            async_copy16(A + (size_t)(m0 + r) * 256 + k0 + kk, &As[wave * 512 + lane * 8]);
        }
#pragma unroll
        for (int c = 0; c < 4; c++) {
            int t = wave * 4 + c;
            int r = t * 16 + rbase;
            async_copy16(W + (size_t)r * 256 + k0 + kk, &Bs[t * 512 + lane * 8]);
        }
        __syncthreads();
        short8 bfr[4];
#pragma unroll
        for (int j = 0; j < 4; j++)
            bfr[j] = *(const short8*)&Bs[(wn + j * 16 + l16) * 32 + quad * 8];
#pragma unroll
        for (int i = 0; i < 4; i++) {
            short8 af = *(const short8*)&As[(i * 16 + l16) * 32 + quad * 8];
#pragma unroll
            for (int j = 0; j < 4; j++)
                acc[i][j] = __builtin_amdgcn_mfma_f32_16x16x32_bf16(af, bfr[j], acc[i][j], 0, 0, 0);
        }
        __syncthreads();
    }

    float bj[4], g1j[4], b1j[4], g2j[4], b2j[4];
#pragma unroll
    for (int j = 0; j < 4; j++) {
        int col = wn + j * 16 + l16;
        bj[j] = bias[col];
        g1j[j] = g1[col]; b1j[j] = b1[col];
        if (LN2) { g2j[j] = g2[col]; b2j[j] = b2[col]; }
    }

    if (!LN2) {
#pragma unroll
        for (int i = 0; i < 4; i++)
#pragma unroll
            for (int rg = 0; rg < 4; rg++) {
                int rl = i * 16 + quad * 4 + rg;
#pragma unroll
                for (int j = 0; j < 4; j++) {
                    int col = wn + j * 16 + l16;
                    acc[i][j][rg] += bj[j] + h[(size_t)(m0 + rl) * 256 + col];
                }
            }
    }
#pragma unroll
    for (int i = 0; i < 4; i++)
#pragma unroll
        for (int rg = 0; rg < 4; rg++) {
            float p = 0.0f, q = 0.0f;
#pragma unroll
            for (int j = 0; j < 4; j++) {
                float v = acc[i][j][rg] + (LN2 ? bj[j] : 0.0f);
                p += v; q += v * v;
            }
#pragma unroll
            for (int off = 1; off < 16; off <<= 1) {
                p += __shfl_xor(p, off);
                q += __shfl_xor(q, off);
            }
            if (l16 == 0) {
                int rl = i * 16 + quad * 4 + rg;
                redS[wave][rl] = p;
                redS2[wave][rl] = q;
            }
        }
    __syncthreads();

    if (!LN2) {
#pragma unroll
        for (int i = 0; i < 4; i++)
#pragma unroll
            for (int rg = 0; rg < 4; rg++) {
                int rl = i * 16 + quad * 4 + rg;
                float s = redS[0][rl] + redS[1][rl] + redS[2][rl] + redS[3][rl];
                float qq = redS2[0][rl] + redS2[1][rl] + redS2[2][rl] + redS2[3][rl];
                float mean = s * (1.0f / 256.0f);
                float rstd = 1.0f / sqrtf(qq * (1.0f / 256.0f) - mean * mean + 1e-5f);
                size_t orow = (size_t)(m0 + rl) * 256;
#pragma unroll
                for (int j = 0; j < 4; j++) {
                    int col = wn + j * 16 + l16;
                    float y = (acc[i][j][rg] - mean) * rstd * g1j[j] + b1j[j];
                    h[orow + col] = y;
                    h_bf[orow + col] = f2bf(y);
                }
            }
    } else {
#pragma unroll
        for (int i = 0; i < 4; i++)
#pragma unroll
            for (int rg = 0; rg < 4; rg++) {
                int rl = i * 16 + quad * 4 + rg;
                float s = redS[0][rl] + redS[1][rl] + redS[2][rl] + redS[3][rl];
                float qq = redS2[0][rl] + redS2[1][rl] + redS2[2][rl] + redS2[3][rl];
                float mean = s * (1.0f / 256.0f);
                float rstd = 1.0f / sqrtf(qq * (1.0f / 256.0f) - mean * mean + 1e-5f);
#pragma unroll
                for (int j = 0; j < 4; j++) {
                    int col = wn + j * 16 + l16;
                    float v = acc[i][j][rg] + bj[j];
                    float hu = (v - mean) * rstd * g1j[j] + b1j[j];
                    acc[i][j][rg] = hu + h[(size_t)(m0 + rl) * 256 + col];
                }
            }
        __syncthreads();
#pragma unroll
        for (int i = 0; i < 4; i++)
#pragma unroll
            for (int rg = 0; rg < 4; rg++) {
                float p = 0.0f, q = 0.0f;
#pragma unroll
                for (int j = 0; j < 4; j++) {
                    float v = acc[i][j][rg];
                    p += v; q += v * v;
                }
#pragma unroll
                for (int off = 1; off < 16; off <<= 1) {
                    p += __shfl_xor(p, off);
                    q += __shfl_xor(q, off);
                }
                if (l16 == 0) {
                    int rl = i * 16 + quad * 4 + rg;
                    redS[wave][rl] = p;
                    redS2[wave][rl] = q;
                }
            }
        __syncthreads();
#pragma unroll
        for (int i = 0; i < 4; i++)
#pragma unroll
            for (int rg = 0; rg < 4; rg++) {
                int rl = i * 16 + quad * 4 + rg;
                float s = redS[0][rl] + redS[1][rl] + redS[2][rl] + redS[3][rl];
                float qq = redS2[0][rl] + redS2[1][rl] + redS2[2][rl] + redS2[3][rl];
                float mean = s * (1.0f / 256.0f);
                float rstd = 1.0f / sqrtf(qq * (1.0f / 256.0f) - mean * mean + 1e-5f);
                size_t orow = (size_t)(m0 + rl) * 256;
#pragma unroll
                for (int j = 0; j < 4; j++) {
                    int col = wn + j * 16 + l16;
                    float y = (acc[i][j][rg] - mean) * rstd * g2j[j] + b2j[j];
                    h[orow + col] = y;
                    h_bf[orow + col] = f2bf(y);
                }
            }
    }
}

// ================= rel / dist (permuted order) =================
__global__ __launch_bounds__(256) void rel_dist_kernel(
    const float* __restrict__ cur, const int* __restrict__ rowi, const int* __restrict__ coli,
    float* __restrict__ rel, float* __restrict__ dist)
{
    const int e = blockIdx.x * 256 + threadIdx.x;
    int r = rowi[e], c = coli[e];
    float rx = cur[(size_t)r * 3 + 0] - cur[(size_t)c * 3 + 0];
    float ry = cur[(size_t)r * 3 + 1] - cur[(size_t)c * 3 + 1];
    float rz = cur[(size_t)r * 3 + 2] - cur[(size_t)c * 3 + 2];
    rel[(size_t)e * 3 + 0] = rx;
    rel[(size_t)e * 3 + 1] = ry;
    rel[(size_t)e * 3 + 2] = rz;
    float dx = rx + 1e-8f, dy = ry + 1e-8f, dz = rz + 1e-8f;
    dist[e] = sqrtf(dx * dx + dy * dy + dz * dz);
}

__global__ __launch_bounds__(256) void cur_update_kernel(
    float* __restrict__ cur, const float* __restrict__ posupd, const float* __restrict__ ps, int l)
{
    const int i = blockIdx.x * 256 + threadIdx.x;
    cur[i] += ps[l] * posupd[i];
}

// ================= pack: hs_bf = bf16(h + hmsg) =================
__global__ __launch_bounds__(256) void pack_add_kernel(
    const float* __restrict__ a, const float* __restrict__ b, unsigned short* __restrict__ o)
{
    const int i = blockIdx.x * 256 + threadIdx.x;
    o[i] = f2bf(a[i] + b[i]);
}

// ================= attention: one block per (graph, head) =================
__global__ __launch_bounds__(64) void attn_kernel(
    const unsigned short* __restrict__ qkv, unsigned short* __restrict__ o)
{
    __shared__ float kS[64][33];
    __shared__ float vS[64][33];
    const int g = blockIdx.x, hh = blockIdx.y;
    const int qi = threadIdx.x;
    const unsigned short* base = qkv + (size_t)(g * 64) * 768 + hh * 32;
    float qreg[32];
#pragma unroll
    for (int d = 0; d < 32; d++) qreg[d] = bf2f(base[(size_t)qi * 768 + d]);
#pragma unroll
    for (int d = 0; d < 32; d++) kS[qi][d] = bf2f(base[(size_t)qi * 768 + 256 + d]);
#pragma unroll
    for (int d = 0; d < 32; d++) vS[qi][d] = bf2f(base[(size_t)qi * 768 + 512 + d]);
    __syncthreads();
    float sreg[64];
    float mx = -1e30f;
    for (int kj = 0; kj < 64; kj++) {
        float s = 0.0f;
#pragma unroll
        for (int d = 0; d < 32; d++) s += qreg[d] * kS[kj][d];
        s *= 0.17677669529663687f;
        sreg[kj] = s;
        mx = fmaxf(mx, s);
    }
    float sum = 0.0f;
    for (int kj = 0; kj < 64; kj++) {
        float p = expf(sreg[kj] - mx);
        sreg[kj] = p;
        sum += p;
    }
    float inv = 1.0f / sum;
    float oacc[32] = {};
    for (int kj = 0; kj < 64; kj++) {
        float p = sreg[kj] * inv;
#pragma unroll
        for (int d = 0; d < 32; d++) oacc[d] += p * vS[kj][d];
    }
    unsigned short* ob = o + (size_t)(g * 64 + qi) * HC + hh * 32;
#pragma unroll
    for (int d = 0; d < 32; d++) ob[d] = f2bf(oacc[d]);
}

extern "C" void kernel_launch(void* const* d_in, const int* in_sizes, int n_in,
                              void* d_out, int out_size, void* d_ws, size_t ws_size,
                              hipStream_t stream)
{
    const float* x    = (const float*)d_in[0];
    const float* pos  = (const float*)d_in[1];
    const int*   ei   = (const int*)d_in[2];
    const float* pe_w1 = (const float*)d_in[5];
    const float* pe_b1 = (const float*)d_in[6];
    const float* pe_w2 = (const float*)d_in[7];
    const float* pe_b2 = (const float*)d_in[8];
    const float* pe_lg = (const float*)d_in[9];
    const float* pe_lb = (const float*)d_in[10];
    const float* ph_w1 = (const float*)d_in[11];
    const float* ph_b1 = (const float*)d_in[12];
    const float* ph_w2 = (const float*)d_in[13];
    const float* ph_b2 = (const float*)d_in[14];
    const float* ph_lg = (const float*)d_in[15];
    const float* ph_lb = (const float*)d_in[16];
    const float* px_w1 = (const float*)d_in[17];
    const float* px_b1 = (const float*)d_in[18];
    const float* px_w2 = (const float*)d_in[19];
    const float* px_b2 = (const float*)d_in[20];
    const float* ain_w = (const float*)d_in[21];
    const float* ain_b = (const float*)d_in[22];
    const float* aout_w = (const float*)d_in[23];
    const float* aout_b = (const float*)d_in[24];
    const float* lnh_g = (const float*)d_in[25];
    const float* lnh_b = (const float*)d_in[26];
    const float* lna_g = (const float*)d_in[27];
    const float* lna_b = (const float*)d_in[28];
    const float* ff_w1 = (const float*)d_in[29];
    const float* ff_b1 = (const float*)d_in[30];
    const float* ff_w2 = (const float*)d_in[31];
    const float* ff_b2 = (const float*)d_in[32];
    const float* ps    = (const float*)d_in[33];

    char* p = (char*)d_ws;
    auto alloc = [&](size_t bytes) { char* r = p; p += (bytes + 63) & ~(size_t)63; return r; };
    float* h      = (float*)alloc((size_t)NTOTC * HC * 4);
    unsigned short* h_bf  = (unsigned short*)alloc((size_t)NTOTC * HC * 2);
    unsigned short* hs_bf = (unsigned short*)alloc((size_t)NTOTC * HC * 2);
    unsigned short* t_bf  = (unsigned short*)alloc((size_t)NTOTC * HC * 2);
    float* cur    = (float*)alloc((size_t)NTOTC * 3 * 4);
    float* relP   = (float*)alloc((size_t)NEDGEC * 3 * 4);
    float* distP  = (float*)alloc((size_t)NEDGEC * 4);
    float* posupd = (float*)alloc((size_t)NTOTC * 3 * 4);
    float* hmsg   = (float*)alloc((size_t)NTOTC * HC * 4);
    unsigned short* qkv_bf = (unsigned short*)alloc((size_t)NTOTC * 3 * HC * 2);
    unsigned short* o_bf   = (unsigned short*)alloc((size_t)NTOTC * HC * 2);
    unsigned short* ff1_bf = (unsigned short*)alloc((size_t)NTOTC * 4 * HC * 2);
    int* cnt  = (int*)alloc(16384 * 4);
    int* ptrw = (int*)alloc(16384 * 4);
    int* rowP = (int*)alloc((size_t)NEDGEC * 4);
    int* colP = (int*)alloc((size_t)NEDGEC * 4);
    unsigned short* w_pe1k = (unsigned short*)alloc((size_t)LC * 256 * 512 * 2);
    float*          w_last = (float*)alloc((size_t)LC * 256 * 4);
    unsigned short* w_pe2  = (unsigned short*)alloc((size_t)LC * 256 * 256 * 2);
    unsigned short* w_ph1  = (unsigned short*)alloc((size_t)LC * 256 * 256 * 2);
    unsigned short* w_ph2  = (unsigned short*)alloc((size_t)LC * 256 * 256 * 2);
    unsigned short* w_px1  = (unsigned short*)alloc((size_t)LC * 256 * 256 * 2);
    unsigned short* w_ain  = (unsigned short*)alloc((size_t)LC * 768 * 256 * 2);
    unsigned short* w_aout = (unsigned short*)alloc((size_t)LC * 256 * 256 * 2);
    unsigned short* w_ff1  = (unsigned short*)alloc((size_t)LC * 1024 * 256 * 2);
    unsigned short* w_ff2  = (unsigned short*)alloc((size_t)LC * 256 * 1024 * 2);

    // ---- counting sort of edges by col (edge_index is constant per call) ----
    hipMemsetAsync(cnt, 0, 16384 * 4, stream);
    hist_kernel<<<NEDGEC / 256, 256, 0, stream>>>(ei + NEDGEC, cnt);
    scan16k_kernel<<<1, 256, 0, stream>>>(cnt, ptrw);
    permute_kernel<<<NEDGEC / 256, 256, 0, stream>>>(ei, ei + NEDGEC, ptrw, rowP, colP);

    // ---- convert weights to bf16 ----
    conv_pe1_kernel<<<(LC * 256 * 513 + 255) / 256, 256, 0, stream>>>(pe_w1, w_pe1k, w_last);
    conv_bf16_kernel<<<1536, 256, 0, stream>>>(pe_w2, w_pe2, LC * 256 * 256);
    conv_bf16_kernel<<<1536, 256, 0, stream>>>(ph_w1, w_ph1, LC * 256 * 256);
    conv_bf16_kernel<<<1536, 256, 0, stream>>>(ph_w2, w_ph2, LC * 256 * 256);
    conv_bf16_kernel<<<1536, 256, 0, stream>>>(px_w1, w_px1, LC * 256 * 256);
    conv_bf16_kernel<<<4608, 256, 0, stream>>>(ain_w, w_ain, LC * 768 * 256);
    conv_bf16_kernel<<<1536, 256, 0, stream>>>(aout_w, w_aout, LC * 256 * 256);
    conv_bf16_kernel<<<6144, 256, 0, stream>>>(ff_w1, w_ff1, LC * 1024 * 256);
    conv_bf16_kernel<<<6144, 256, 0, stream>>>(ff_w2, w_ff2, LC * 256 * 1024);

    hipMemcpyAsync(h, x, (size_t)NTOTC * HC * 4, hipMemcpyDeviceToDevice, stream);
    hipMemcpyAsync(cur, pos, (size_t)NTOTC * 3 * 4, hipMemcpyDeviceToDevice, stream);
    conv_bf16_kernel<<<4096, 256, 0, stream>>>(x, h_bf, NTOTC * HC);

    for (int l = 0; l < LC; l++) {
        rel_dist_kernel<<<NEDGEC / 256, 256, 0, stream>>>(cur, rowP, colP, relP, distP);
        hipMemsetAsync(hmsg, 0, (size_t)NTOTC * HC * 4, stream);
        hipMemsetAsync(posupd, 0, (size_t)NTOTC * 3 * 4, stream);

        fused_edge_kernel<<<NEDGEC / 64, 256, 0, stream>>>(
            h_bf, rowP, colP, distP, relP,
            w_pe1k + (size_t)l * 256 * 512, w_last + (size_t)l * 256, pe_b1 + (size_t)l * HC,
            w_pe2 + (size_t)l * 256 * 256, pe_b2 + (size_t)l * HC,
            pe_lg + (size_t)l * HC, pe_lb + (size_t)l * HC,
            w_px1 + (size_t)l * 256 * 256, px_b1 + (size_t)l * HC,
            px_w2 + (size_t)l * HC, px_b2 + l,
            hmsg, posupd);

        // phi_h tail
        pack_add_kernel<<<NTOTC * HC / 256, 256, 0, stream>>>(h, hmsg, hs_bf);
        mgemm_kernel<1, false, false, true><<<dim3(NTOTC / 128, 2), 256, 0, stream>>>(
            hs_bf, w_ph1 + (size_t)l * 256 * 256, ph_b1 + (size_t)l * HC,
            nullptr, nullptr, t_bf, NTOTC, HC, HC);
        node_fused_kernel<true><<<NTOTC / 64, 256, 0, stream>>>(
            t_bf, w_ph2 + (size_t)l * 256 * 256, ph_b2 + (size_t)l * HC,
            ph_lg + (size_t)l * HC, ph_lb + (size_t)l * HC,
            lnh_g + (size_t)l * HC, lnh_b + (size_t)l * HC, h, h_bf);
        cur_update_kernel<<<(NTOTC * 3) / 256, 256, 0, stream>>>(cur, posupd, ps, l);

        // attention
        mgemm_kernel<0, false, false, true><<<dim3(NTOTC / 128, 6), 256, 0, stream>>>(
            h_bf, w_ain + (size_t)l * 768 * 256, ain_b + (size_t)l * 3 * HC,
            nullptr, nullptr, qkv_bf, NTOTC, 3 * HC, HC);
        attn_kernel<<<dim3(NTOTC / 64, NHEADSC), 64, 0, stream>>>(qkv_bf, o_bf);
        node_fused_kernel<false><<<NTOTC / 64, 256, 0, stream>>>(
            o_bf, w_aout + (size_t)l * 256 * 256, aout_b + (size_t)l * HC,
            lna_g + (size_t)l * HC, lna_b + (size_t)l * HC,
            nullptr, nullptr, h, h_bf);

        // feed-forward with residual
        mgemm_kernel<2, false, false, true><<<dim3(NTOTC / 128, 8), 256, 0, stream>>>(
            h_bf, w_ff1 + (size_t)l * 1024 * 256, ff_b1 + (size_t)l * 4 * HC,
            nullptr, nullptr, ff1_bf, NTOTC, 4 * HC, HC);
        mgemm_kernel<0, true, true, true><<<dim3(NTOTC / 128, 2), 256, 0, stream>>>(
            ff1_bf, w_ff2 + (size_t)l * 256 * 1024, ff_b2 + (size_t)l * HC,
            h, h, h_bf, NTOTC, HC, 4 * HC);
    }

    hipMemcpyAsync(d_out, h, (size_t)NTOTC * HC * 4, hipMemcpyDeviceToDevice, stream);
    hipMemcpyAsync((float*)d_out + (size_t)NTOTC * HC, cur, (size_t)NTOTC * 3 * 4,
                   hipMemcpyDeviceToDevice, stream);
}

// Round 5
// 3493.205 us; speedup vs baseline: 5.4754x; 1.3943x over previous
//
#include <hip/hip_runtime.h>
#include <cstddef>
#include <cstdint>

#define NTOTC 16384
#define HC 256
#define LC 6
#define NEDGEC 262144
#define NHEADSC 8

typedef __attribute__((ext_vector_type(8))) short short8;
typedef __attribute__((ext_vector_type(4))) float f32x4;

__device__ __forceinline__ unsigned short f2bf(float f) {
    unsigned int u = __float_as_uint(f);
    u += 0x7fff + ((u >> 16) & 1);   // round-to-nearest-even
    return (unsigned short)(u >> 16);
}
__device__ __forceinline__ float bf2f(unsigned short s) {
    return __uint_as_float(((unsigned int)s) << 16);
}
__device__ __forceinline__ void async_copy16(const void* g, void* l) {
    __builtin_amdgcn_global_load_lds(
        (const __attribute__((address_space(1))) unsigned int*)g,
        (__attribute__((address_space(3))) unsigned int*)l, 16, 0, 0);
}
// fast transcendentals (v_exp_f32 / v_rcp_f32); ~1e-6 rel err, negligible vs bf16
__device__ __forceinline__ float exp_f(float v) {
    return __builtin_amdgcn_exp2f(v * 1.4426950408889634f);
}
__device__ __forceinline__ float silu_f(float v) {
    return v * __builtin_amdgcn_rcpf(1.0f + __builtin_amdgcn_exp2f(-v * 1.4426950408889634f));
}
__device__ __forceinline__ float tanh_f(float v) {
    float e = __builtin_amdgcn_exp2f(v * 2.8853900817779268f);   // e^(2v)
    return 1.0f - 2.0f * __builtin_amdgcn_rcpf(1.0f + e);
}

// ================= weight conversion =================
__global__ __launch_bounds__(256) void conv_bf16_kernel(
    const float* __restrict__ in, unsigned short* __restrict__ out, int n)
{
    for (int i = blockIdx.x * 256 + threadIdx.x; i < n; i += gridDim.x * 256)
        out[i] = f2bf(in[i]);
}

// phi_e_w1 [L,256,513] -> bf16 [L,256,512] + fp32 last column [L,256]
__global__ __launch_bounds__(256) void conv_pe1_kernel(
    const float* __restrict__ in, unsigned short* __restrict__ outk, float* __restrict__ wlast)
{
    int idx = blockIdx.x * 256 + threadIdx.x;
    if (idx >= LC * 256 * 513) return;
    int k = idx % 513;
    int nl = idx / 513;
    float v = in[idx];
    if (k == 512) wlast[nl] = v;
    else outk[(size_t)nl * 512 + k] = f2bf(v);
}

// ================= counting sort of edges by col =================
__global__ __launch_bounds__(256) void hist_kernel(
    const int* __restrict__ col, int* __restrict__ cnt)
{
    int e = blockIdx.x * 256 + threadIdx.x;
    atomicAdd(&cnt[col[e]], 1);
}

__global__ __launch_bounds__(256) void scan16k_kernel(
    const int* __restrict__ cnt, int* __restrict__ ptrw)
{
    __shared__ int partial[256];
    const int t = threadIdx.x;
    const int base = t * 64;
    int loc[64];
    int s = 0;
#pragma unroll
    for (int i = 0; i < 64; i++) { loc[i] = s; s += cnt[base + i]; }
    partial[t] = s;
    __syncthreads();
    if (t == 0) {
        int run = 0;
        for (int i = 0; i < 256; i++) { int tmp = partial[i]; partial[i] = run; run += tmp; }
    }
    __syncthreads();
    int off = partial[t];
#pragma unroll
    for (int i = 0; i < 64; i++) ptrw[base + i] = off + loc[i];
}

__global__ __launch_bounds__(256) void permute_kernel(
    const int* __restrict__ row, const int* __restrict__ col, int* __restrict__ ptrw,
    int* __restrict__ rowP, int* __restrict__ colP)
{
    int e = blockIdx.x * 256 + threadIdx.x;
    int c = col[e];
    int pos = atomicAdd(&ptrw[c], 1);
    rowP[pos] = row[e];
    colP[pos] = c;
}

// ================= generic MFMA GEMM: C = act(A @ W^T + bias)(+R) =================
template<int ACT, bool RES, bool WF, bool WB>
__global__ __launch_bounds__(256) void mgemm_kernel(
    const unsigned short* __restrict__ A, const unsigned short* __restrict__ W,
    const float* __restrict__ bias, const float* __restrict__ R,
    float* __restrict__ Cf, unsigned short* __restrict__ Cb,
    int M, int N, int K)
{
    __shared__ unsigned short As[128 * 32];
    __shared__ unsigned short Bs[128 * 32];
    const int tid = threadIdx.x;
    const int lane = tid & 63, wave = tid >> 6;
    const int quad = lane >> 4, l16 = lane & 15;
    const int wm = (wave >> 1) * 64, wn = (wave & 1) * 64;
    const int m0 = blockIdx.x * 128, n0 = blockIdx.y * 128;
    f32x4 acc[4][4] = {};
    const int rbase = (lane >> 2);
    const int kk = (lane & 3) * 8;

    for (int k0 = 0; k0 < K; k0 += 32) {
#pragma unroll
        for (int c = 0; c < 2; c++) {
            int t = wave * 2 + c;
            int r = t * 16 + rbase;
            async_copy16(A + (size_t)(m0 + r) * K + k0 + kk, &As[t * 512 + lane * 8]);
            async_copy16(W + (size_t)(n0 + r) * K + k0 + kk, &Bs[t * 512 + lane * 8]);
        }
        __syncthreads();
        short8 af[4], bfr[4];
#pragma unroll
        for (int i = 0; i < 4; i++)
            af[i] = *(const short8*)&As[(wm + i * 16 + l16) * 32 + quad * 8];
#pragma unroll
        for (int j = 0; j < 4; j++)
            bfr[j] = *(const short8*)&Bs[(wn + j * 16 + l16) * 32 + quad * 8];
#pragma unroll
        for (int i = 0; i < 4; i++)
#pragma unroll
            for (int j = 0; j < 4; j++)
                acc[i][j] = __builtin_amdgcn_mfma_f32_16x16x32_bf16(af[i], bfr[j], acc[i][j], 0, 0, 0);
        __syncthreads();
    }
#pragma unroll
    for (int j = 0; j < 4; j++) {
        int col = n0 + wn + j * 16 + l16;
        float bi = bias[col];
#pragma unroll
        for (int i = 0; i < 4; i++) {
#pragma unroll
            for (int rg = 0; rg < 4; rg++) {
                int row = m0 + wm + i * 16 + quad * 4 + rg;
                float v = acc[i][j][rg] + bi;
                if (ACT == 1) v = silu_f(v);
                if (ACT == 2) v = 0.5f * v * (1.0f + erff(v * 0.7071067811865476f));
                if (RES) v += R[(size_t)row * N + col];
                if (WF) Cf[(size_t)row * N + col] = v;
                if (WB) Cb[(size_t)row * N + col] = f2bf(v);
            }
        }
    }
}

// ================= FULLY FUSED edge pipeline (BK=64) =================
// Per block: 64 col-sorted edges, all 256 output cols, 4 waves split N.
__global__ __launch_bounds__(256, 2) void fused_edge_kernel(
    const unsigned short* __restrict__ hB,
    const int* __restrict__ rowP, const int* __restrict__ colP,
    const float* __restrict__ distv, const float* __restrict__ relv,
    const unsigned short* __restrict__ W1, const float* __restrict__ wlast,
    const float* __restrict__ b1,
    const unsigned short* __restrict__ W2, const float* __restrict__ b2,
    const float* __restrict__ lg, const float* __restrict__ lb,
    const unsigned short* __restrict__ W3, const float* __restrict__ b3,
    const float* __restrict__ w2v, const float* __restrict__ b2s,
    float* __restrict__ hmsg, float* __restrict__ posupd)
{
    __shared__ unsigned short As[64 * 64];      // 8 KB
    __shared__ unsigned short Bs[256 * 64];     // 32 KB
    __shared__ unsigned short tS[64 * 264];     // 33.8 KB (stride 264 shorts, 16B aligned)
    __shared__ float redS[4][64];
    __shared__ float redS2[4][64];
    __shared__ int rowS[64], colS[64], flagS[64];
    __shared__ float distS[64];
    __shared__ float relS[64][3];
    __shared__ float cfS[64];

    const int tid = threadIdx.x;
    const int lane = tid & 63, wave = tid >> 6;
    const int quad = lane >> 4, l16 = lane & 15;
    const int wn = wave * 64;
    const int m0 = blockIdx.x * 64;

    if (tid < 64) {
        rowS[tid] = rowP[m0 + tid];
        colS[tid] = colP[m0 + tid];
        distS[tid] = distv[m0 + tid];
        relS[tid][0] = relv[(size_t)(m0 + tid) * 3 + 0];
        relS[tid][1] = relv[(size_t)(m0 + tid) * 3 + 1];
        relS[tid][2] = relv[(size_t)(m0 + tid) * 3 + 2];
    }
    __syncthreads();
    if (tid < 64) flagS[tid] = (tid == 63) || (colS[tid] != colS[tid + 1]);
    // flagS consumed only after many barriers below

    f32x4 acc[4][4] = {};

    // ---- GEMM1: K=512 (gathered h), BK=64 ----
    for (int k0 = 0; k0 < 512; k0 += 64) {
        const int half = k0 >> 8;
        const int kb = k0 & 255;
#pragma unroll
        for (int c = 0; c < 2; c++) {
            int u = c * 256 + tid;           // 0..511
            int r = u >> 3, kg = u & 7;      // row 0..63, kgroup 0..7
            int node = half ? colS[r] : rowS[r];
            async_copy16(hB + (size_t)node * 256 + kb + kg * 8, &As[u * 8]);
        }
#pragma unroll
        for (int c = 0; c < 8; c++) {
            int u = c * 256 + tid;           // 0..2047
            int r = u >> 3, kg = u & 7;      // N-row 0..255
            async_copy16(W1 + (size_t)r * 512 + k0 + kg * 8, &Bs[u * 8]);
        }
        __syncthreads();
        short8 af[2][4], bfr[2][4];
#pragma unroll
        for (int ks = 0; ks < 2; ks++) {
#pragma unroll
            for (int j = 0; j < 4; j++)
                bfr[ks][j] = *(const short8*)&Bs[(wn + j * 16 + l16) * 64 + ks * 32 + quad * 8];
#pragma unroll
            for (int i = 0; i < 4; i++)
                af[ks][i] = *(const short8*)&As[(i * 16 + l16) * 64 + ks * 32 + quad * 8];
        }
#pragma unroll
        for (int ks = 0; ks < 2; ks++)
#pragma unroll
            for (int i = 0; i < 4; i++)
#pragma unroll
                for (int j = 0; j < 4; j++)
                    acc[i][j] = __builtin_amdgcn_mfma_f32_16x16x32_bf16(af[ks][i], bfr[ks][j], acc[i][j], 0, 0, 0);
        __syncthreads();
    }
    // epilogue 1: silu(acc + dist*wlast + b1) -> tS
    {
        float wlj[4], b1j[4];
#pragma unroll
        for (int j = 0; j < 4; j++) {
            int col = wn + j * 16 + l16;
            wlj[j] = wlast[col];
            b1j[j] = b1[col];
        }
#pragma unroll
        for (int i = 0; i < 4; i++)
#pragma unroll
            for (int rg = 0; rg < 4; rg++) {
                int row = i * 16 + quad * 4 + rg;
                float dv = distS[row];
#pragma unroll
                for (int j = 0; j < 4; j++) {
                    int col = wn + j * 16 + l16;
                    float v = acc[i][j][rg] + dv * wlj[j] + b1j[j];
                    tS[row * 264 + col] = f2bf(silu_f(v));
                }
            }
    }
    __syncthreads();

    // ---- GEMM2: K=256, A from tS, BK=64 ----
#pragma unroll
    for (int i = 0; i < 4; i++)
#pragma unroll
        for (int j = 0; j < 4; j++) acc[i][j] = (f32x4){0.f, 0.f, 0.f, 0.f};
    for (int k0 = 0; k0 < 256; k0 += 64) {
#pragma unroll
        for (int c = 0; c < 8; c++) {
            int u = c * 256 + tid;
            int r = u >> 3, kg = u & 7;
            async_copy16(W2 + (size_t)r * 256 + k0 + kg * 8, &Bs[u * 8]);
        }
        __syncthreads();
        short8 af[2][4], bfr[2][4];
#pragma unroll
        for (int ks = 0; ks < 2; ks++) {
#pragma unroll
            for (int j = 0; j < 4; j++)
                bfr[ks][j] = *(const short8*)&Bs[(wn + j * 16 + l16) * 64 + ks * 32 + quad * 8];
#pragma unroll
            for (int i = 0; i < 4; i++)
                af[ks][i] = *(const short8*)&tS[(i * 16 + l16) * 264 + k0 + ks * 32 + quad * 8];
        }
#pragma unroll
        for (int ks = 0; ks < 2; ks++)
#pragma unroll
            for (int i = 0; i < 4; i++)
#pragma unroll
                for (int j = 0; j < 4; j++)
                    acc[i][j] = __builtin_amdgcn_mfma_f32_16x16x32_bf16(af[ks][i], bfr[ks][j], acc[i][j], 0, 0, 0);
        __syncthreads();
    }
    // epilogue 2: LN -> m -> tS (overwrite)
    {
        float b2j[4], gj[4], bbj[4];
#pragma unroll
        for (int j = 0; j < 4; j++) {
            int col = wn + j * 16 + l16;
            b2j[j] = b2[col];
            gj[j] = lg[col];
            bbj[j] = lb[col];
        }
#pragma unroll
        for (int i = 0; i < 4; i++)
#pragma unroll
            for (int rg = 0; rg < 4; rg++) {
                float p = 0.0f, q = 0.0f;
#pragma unroll
                for (int j = 0; j < 4; j++) {
                    float v = acc[i][j][rg] + b2j[j];
                    p += v; q += v * v;
                }
#pragma unroll
                for (int off = 1; off < 16; off <<= 1) {
                    p += __shfl_xor(p, off);
                    q += __shfl_xor(q, off);
                }
                if (l16 == 0) {
                    int row = i * 16 + quad * 4 + rg;
                    redS[wave][row] = p;
                    redS2[wave][row] = q;
                }
            }
        __syncthreads();
#pragma unroll
        for (int i = 0; i < 4; i++)
#pragma unroll
            for (int rg = 0; rg < 4; rg++) {
                int row = i * 16 + quad * 4 + rg;
                float s = redS[0][row] + redS[1][row] + redS[2][row] + redS[3][row];
                float qq = redS2[0][row] + redS2[1][row] + redS2[2][row] + redS2[3][row];
                float mean = s * (1.0f / 256.0f);
                float rstd = 1.0f / sqrtf(qq * (1.0f / 256.0f) - mean * mean + 1e-5f);
#pragma unroll
                for (int j = 0; j < 4; j++) {
                    int col = wn + j * 16 + l16;
                    float v = acc[i][j][rg] + b2j[j];
                    tS[row * 264 + col] = f2bf((v - mean) * rstd * gj[j] + bbj[j]);
                }
            }
    }
    __syncthreads();

    // ---- segmented scatter of m into hmsg: fixed unrolled loop, uniform branch ----
    {
        const int c = tid;   // hidden col
        float s = 0.0f;
#pragma unroll
        for (int r = 0; r < 64; r++) {
            s += bf2f(tS[r * 264 + c]);
            if (flagS[r]) {   // block-uniform
                atomicAdd(&hmsg[(size_t)colS[r] * 256 + c], s);
                s = 0.0f;
            }
        }
    }

    // ---- GEMM3: K=256, A = m from tS, BK=64 ----
#pragma unroll
    for (int i = 0; i < 4; i++)
#pragma unroll
        for (int j = 0; j < 4; j++) acc[i][j] = (f32x4){0.f, 0.f, 0.f, 0.f};
    for (int k0 = 0; k0 < 256; k0 += 64) {
#pragma unroll
        for (int c = 0; c < 8; c++) {
            int u = c * 256 + tid;
            int r = u >> 3, kg = u & 7;
            async_copy16(W3 + (size_t)r * 256 + k0 + kg * 8, &Bs[u * 8]);
        }
        __syncthreads();
        short8 af[2][4], bfr[2][4];
#pragma unroll
        for (int ks = 0; ks < 2; ks++) {
#pragma unroll
            for (int j = 0; j < 4; j++)
                bfr[ks][j] = *(const short8*)&Bs[(wn + j * 16 + l16) * 64 + ks * 32 + quad * 8];
#pragma unroll
            for (int i = 0; i < 4; i++)
                af[ks][i] = *(const short8*)&tS[(i * 16 + l16) * 264 + k0 + ks * 32 + quad * 8];
        }
#pragma unroll
        for (int ks = 0; ks < 2; ks++)
#pragma unroll
            for (int i = 0; i < 4; i++)
#pragma unroll
                for (int j = 0; j < 4; j++)
                    acc[i][j] = __builtin_amdgcn_mfma_f32_16x16x32_bf16(af[ks][i], bfr[ks][j], acc[i][j], 0, 0, 0);
        __syncthreads();
    }
    // epilogue 3: coeff = tanh(dot(silu(acc+b3), w2v) + b2s); posupd scatter
    {
        float b3j[4], w2j[4];
#pragma unroll
        for (int j = 0; j < 4; j++) {
            int col = wn + j * 16 + l16;
            b3j[j] = b3[col];
            w2j[j] = w2v[col];
        }
#pragma unroll
        for (int i = 0; i < 4; i++)
#pragma unroll
            for (int rg = 0; rg < 4; rg++) {
                float p = 0.0f;
#pragma unroll
                for (int j = 0; j < 4; j++)
                    p += silu_f(acc[i][j][rg] + b3j[j]) * w2j[j];
#pragma unroll
                for (int off = 1; off < 16; off <<= 1) p += __shfl_xor(p, off);
                if (l16 == 0) redS[wave][i * 16 + quad * 4 + rg] = p;
            }
        __syncthreads();
        if (tid < 64) {
            float tot = redS[0][tid] + redS[1][tid] + redS[2][tid] + redS[3][tid] + b2s[0];
            cfS[tid] = tanh_f(tot);
        }
        __syncthreads();
        if (tid < 3) {
            const int comp = tid;
            float s = 0.0f;
#pragma unroll
            for (int r = 0; r < 64; r++) {
                s += relS[r][comp] * cfS[r];
                if (flagS[r]) {
                    atomicAdd(&posupd[(size_t)colS[r] * 3 + comp], s);
                    s = 0.0f;
                }
            }
        }
    }
}

// ============ fused node GEMM + LN epilogue ============
template<bool LN2>
__global__ __launch_bounds__(256) void node_fused_kernel(
    const unsigned short* __restrict__ A, const unsigned short* __restrict__ W,
    const float* __restrict__ bias,
    const float* __restrict__ g1, const float* __restrict__ b1,
    const float* __restrict__ g2, const float* __restrict__ b2,
    float* __restrict__ h, unsigned short* __restrict__ h_bf)
{
    __shared__ unsigned short As[64 * 32];
    __shared__ unsigned short Bs[256 * 32];
    __shared__ float redS[4][64];
    __shared__ float redS2[4][64];
    const int tid = threadIdx.x;
    const int lane = tid & 63, wave = tid >> 6;
    const int quad = lane >> 4, l16 = lane & 15;
    const int wn = wave * 64;
    const int m0 = blockIdx.x * 64;
    f32x4 acc[4][4] = {};
    const int rbase = (lane >> 2);
    const int kk = (lane & 3) * 8;

    for (int k0 = 0; k0 < 256; k0 += 32) {
        {
            int r = wave * 16 + rbase;
            async_copy16(A + (size_t)(m0 + r) * 256 + k0 + kk, &As[wave * 512 + lane * 8]);
        }
#pragma unroll
        for (int c = 0; c < 4; c++) {
            int t = wave * 4 + c;
            int r = t * 16 + rbase;
            async_copy16(W + (size_t)r * 256 + k0 + kk, &Bs[t * 512 + lane * 8]);
        }
        __syncthreads();
        short8 bfr[4];
#pragma unroll
        for (int j = 0; j < 4; j++)
            bfr[j] = *(const short8*)&Bs[(wn + j * 16 + l16) * 32 + quad * 8];
#pragma unroll
        for (int i = 0; i < 4; i++) {
            short8 af = *(const short8*)&As[(i * 16 + l16) * 32 + quad * 8];
#pragma unroll
            for (int j = 0; j < 4; j++)
                acc[i][j] = __builtin_amdgcn_mfma_f32_16x16x32_bf16(af, bfr[j], acc[i][j], 0, 0, 0);
        }
        __syncthreads();
    }

    float bj[4], g1j[4], b1j[4], g2j[4], b2j[4];
#pragma unroll
    for (int j = 0; j < 4; j++) {
        int col = wn + j * 16 + l16;
        bj[j] = bias[col];
        g1j[j] = g1[col]; b1j[j] = b1[col];
        if (LN2) { g2j[j] = g2[col]; b2j[j] = b2[col]; }
    }

    if (!LN2) {
#pragma unroll
        for (int i = 0; i < 4; i++)
#pragma unroll
            for (int rg = 0; rg < 4; rg++) {
                int rl = i * 16 + quad * 4 + rg;
#pragma unroll
                for (int j = 0; j < 4; j++) {
                    int col = wn + j * 16 + l16;
                    acc[i][j][rg] += bj[j] + h[(size_t)(m0 + rl) * 256 + col];
                }
            }
    }
#pragma unroll
    for (int i = 0; i < 4; i++)
#pragma unroll
        for (int rg = 0; rg < 4; rg++) {
            float p = 0.0f, q = 0.0f;
#pragma unroll
            for (int j = 0; j < 4; j++) {
                float v = acc[i][j][rg] + (LN2 ? bj[j] : 0.0f);
                p += v; q += v * v;
            }
#pragma unroll
            for (int off = 1; off < 16; off <<= 1) {
                p += __shfl_xor(p, off);
                q += __shfl_xor(q, off);
            }
            if (l16 == 0) {
                int rl = i * 16 + quad * 4 + rg;
                redS[wave][rl] = p;
                redS2[wave][rl] = q;
            }
        }
    __syncthreads();

    if (!LN2) {
#pragma unroll
        for (int i = 0; i < 4; i++)
#pragma unroll
            for (int rg = 0; rg < 4; rg++) {
                int rl = i * 16 + quad * 4 + rg;
                float s = redS[0][rl] + redS[1][rl] + redS[2][rl] + redS[3][rl];
                float qq = redS2[0][rl] + redS2[1][rl] + redS2[2][rl] + redS2[3][rl];
                float mean = s * (1.0f / 256.0f);
                float rstd = 1.0f / sqrtf(qq * (1.0f / 256.0f) - mean * mean + 1e-5f);
                size_t orow = (size_t)(m0 + rl) * 256;
#pragma unroll
                for (int j = 0; j < 4; j++) {
                    int col = wn + j * 16 + l16;
                    float y = (acc[i][j][rg] - mean) * rstd * g1j[j] + b1j[j];
                    h[orow + col] = y;
                    h_bf[orow + col] = f2bf(y);
                }
            }
    } else {
#pragma unroll
        for (int i = 0; i < 4; i++)
#pragma unroll
            for (int rg = 0; rg < 4; rg++) {
                int rl = i * 16 + quad * 4 + rg;
                float s = redS[0][rl] + redS[1][rl] + redS[2][rl] + redS[3][rl];
                float qq = redS2[0][rl] + redS2[1][rl] + redS2[2][rl] + redS2[3][rl];
                float mean = s * (1.0f / 256.0f);
                float rstd = 1.0f / sqrtf(qq * (1.0f / 256.0f) - mean * mean + 1e-5f);
#pragma unroll
                for (int j = 0; j < 4; j++) {
                    int col = wn + j * 16 + l16;
                    float v = acc[i][j][rg] + bj[j];
                    float hu = (v - mean) * rstd * g1j[j] + b1j[j];
                    acc[i][j][rg] = hu + h[(size_t)(m0 + rl) * 256 + col];
                }
            }
        __syncthreads();
#pragma unroll
        for (int i = 0; i < 4; i++)
#pragma unroll
            for (int rg = 0; rg < 4; rg++) {
                float p = 0.0f, q = 0.0f;
#pragma unroll
                for (int j = 0; j < 4; j++) {
                    float v = acc[i][j][rg];
                    p += v; q += v * v;
                }
#pragma unroll
                for (int off = 1; off < 16; off <<= 1) {
                    p += __shfl_xor(p, off);
                    q += __shfl_xor(q, off);
                }
                if (l16 == 0) {
                    int rl = i * 16 + quad * 4 + rg;
                    redS[wave][rl] = p;
                    redS2[wave][rl] = q;
                }
            }
        __syncthreads();
#pragma unroll
        for (int i = 0; i < 4; i++)
#pragma unroll
            for (int rg = 0; rg < 4; rg++) {
                int rl = i * 16 + quad * 4 + rg;
                float s = redS[0][rl] + redS[1][rl] + redS[2][rl] + redS[3][rl];
                float qq = redS2[0][rl] + redS2[1][rl] + redS2[2][rl] + redS2[3][rl];
                float mean = s * (1.0f / 256.0f);
                float rstd = 1.0f / sqrtf(qq * (1.0f / 256.0f) - mean * mean + 1e-5f);
                size_t orow = (size_t)(m0 + rl) * 256;
#pragma unroll
                for (int j = 0; j < 4; j++) {
                    int col = wn + j * 16 + l16;
                    float y = (acc[i][j][rg] - mean) * rstd * g2j[j] + b2j[j];
                    h[orow + col] = y;
                    h_bf[orow + col] = f2bf(y);
                }
            }
    }
}

// ================= rel / dist (permuted order) =================
__global__ __launch_bounds__(256) void rel_dist_kernel(
    const float* __restrict__ cur, const int* __restrict__ rowi, const int* __restrict__ coli,
    float* __restrict__ rel, float* __restrict__ dist)
{
    const int e = blockIdx.x * 256 + threadIdx.x;
    int r = rowi[e], c = coli[e];
    float rx = cur[(size_t)r * 3 + 0] - cur[(size_t)c * 3 + 0];
    float ry = cur[(size_t)r * 3 + 1] - cur[(size_t)c * 3 + 1];
    float rz = cur[(size_t)r * 3 + 2] - cur[(size_t)c * 3 + 2];
    rel[(size_t)e * 3 + 0] = rx;
    rel[(size_t)e * 3 + 1] = ry;
    rel[(size_t)e * 3 + 2] = rz;
    float dx = rx + 1e-8f, dy = ry + 1e-8f, dz = rz + 1e-8f;
    dist[e] = sqrtf(dx * dx + dy * dy + dz * dz);
}

__global__ __launch_bounds__(256) void cur_update_kernel(
    float* __restrict__ cur, const float* __restrict__ posupd, const float* __restrict__ ps, int l)
{
    const int i = blockIdx.x * 256 + threadIdx.x;
    cur[i] += ps[l] * posupd[i];
}

// ================= pack: hs_bf = bf16(h + hmsg) =================
__global__ __launch_bounds__(256) void pack_add_kernel(
    const float* __restrict__ a, const float* __restrict__ b, unsigned short* __restrict__ o)
{
    const int i = blockIdx.x * 256 + threadIdx.x;
    o[i] = f2bf(a[i] + b[i]);
}

// ================= attention: one block per (graph, head) =================
__global__ __launch_bounds__(64) void attn_kernel(
    const unsigned short* __restrict__ qkv, unsigned short* __restrict__ o)
{
    __shared__ float kS[64][33];
    __shared__ float vS[64][33];
    const int g = blockIdx.x, hh = blockIdx.y;
    const int qi = threadIdx.x;
    const unsigned short* base = qkv + (size_t)(g * 64) * 768 + hh * 32;
    float qreg[32];
#pragma unroll
    for (int d = 0; d < 32; d++) qreg[d] = bf2f(base[(size_t)qi * 768 + d]);
#pragma unroll
    for (int d = 0; d < 32; d++) kS[qi][d] = bf2f(base[(size_t)qi * 768 + 256 + d]);
#pragma unroll
    for (int d = 0; d < 32; d++) vS[qi][d] = bf2f(base[(size_t)qi * 768 + 512 + d]);
    __syncthreads();
    float sreg[64];
    float mx = -1e30f;
    for (int kj = 0; kj < 64; kj++) {
        float s = 0.0f;
#pragma unroll
        for (int d = 0; d < 32; d++) s += qreg[d] * kS[kj][d];
        s *= 0.17677669529663687f;
        sreg[kj] = s;
        mx = fmaxf(mx, s);
    }
    float sum = 0.0f;
    for (int kj = 0; kj < 64; kj++) {
        float p = exp_f(sreg[kj] - mx);
        sreg[kj] = p;
        sum += p;
    }
    float inv = 1.0f / sum;
    float oacc[32] = {};
    for (int kj = 0; kj < 64; kj++) {
        float p = sreg[kj] * inv;
#pragma unroll
        for (int d = 0; d < 32; d++) oacc[d] += p * vS[kj][d];
    }
    unsigned short* ob = o + (size_t)(g * 64 + qi) * HC + hh * 32;
#pragma unroll
    for (int d = 0; d < 32; d++) ob[d] = f2bf(oacc[d]);
}

extern "C" void kernel_launch(void* const* d_in, const int* in_sizes, int n_in,
                              void* d_out, int out_size, void* d_ws, size_t ws_size,
                              hipStream_t stream)
{
    const float* x    = (const float*)d_in[0];
    const float* pos  = (const float*)d_in[1];
    const int*   ei   = (const int*)d_in[2];
    const float* pe_w1 = (const float*)d_in[5];
    const float* pe_b1 = (const float*)d_in[6];
    const float* pe_w2 = (const float*)d_in[7];
    const float* pe_b2 = (const float*)d_in[8];
    const float* pe_lg = (const float*)d_in[9];
    const float* pe_lb = (const float*)d_in[10];
    const float* ph_w1 = (const float*)d_in[11];
    const float* ph_b1 = (const float*)d_in[12];
    const float* ph_w2 = (const float*)d_in[13];
    const float* ph_b2 = (const float*)d_in[14];
    const float* ph_lg = (const float*)d_in[15];
    const float* ph_lb = (const float*)d_in[16];
    const float* px_w1 = (const float*)d_in[17];
    const float* px_b1 = (const float*)d_in[18];
    const float* px_w2 = (const float*)d_in[19];
    const float* px_b2 = (const float*)d_in[20];
    const float* ain_w = (const float*)d_in[21];
    const float* ain_b = (const float*)d_in[22];
    const float* aout_w = (const float*)d_in[23];
    const float* aout_b = (const float*)d_in[24];
    const float* lnh_g = (const float*)d_in[25];
    const float* lnh_b = (const float*)d_in[26];
    const float* lna_g = (const float*)d_in[27];
    const float* lna_b = (const float*)d_in[28];
    const float* ff_w1 = (const float*)d_in[29];
    const float* ff_b1 = (const float*)d_in[30];
    const float* ff_w2 = (const float*)d_in[31];
    const float* ff_b2 = (const float*)d_in[32];
    const float* ps    = (const float*)d_in[33];

    char* p = (char*)d_ws;
    auto alloc = [&](size_t bytes) { char* r = p; p += (bytes + 63) & ~(size_t)63; return r; };
    float* h      = (float*)alloc((size_t)NTOTC * HC * 4);
    unsigned short* h_bf  = (unsigned short*)alloc((size_t)NTOTC * HC * 2);
    unsigned short* hs_bf = (unsigned short*)alloc((size_t)NTOTC * HC * 2);
    unsigned short* t_bf  = (unsigned short*)alloc((size_t)NTOTC * HC * 2);
    float* cur    = (float*)alloc((size_t)NTOTC * 3 * 4);
    float* relP   = (float*)alloc((size_t)NEDGEC * 3 * 4);
    float* distP  = (float*)alloc((size_t)NEDGEC * 4);
    float* posupd = (float*)alloc((size_t)NTOTC * 3 * 4);
    float* hmsg   = (float*)alloc((size_t)NTOTC * HC * 4);
    unsigned short* qkv_bf = (unsigned short*)alloc((size_t)NTOTC * 3 * HC * 2);
    unsigned short* o_bf   = (unsigned short*)alloc((size_t)NTOTC * HC * 2);
    unsigned short* ff1_bf = (unsigned short*)alloc((size_t)NTOTC * 4 * HC * 2);
    int* cnt  = (int*)alloc(16384 * 4);
    int* ptrw = (int*)alloc(16384 * 4);
    int* rowP = (int*)alloc((size_t)NEDGEC * 4);
    int* colP = (int*)alloc((size_t)NEDGEC * 4);
    unsigned short* w_pe1k = (unsigned short*)alloc((size_t)LC * 256 * 512 * 2);
    float*          w_last = (float*)alloc((size_t)LC * 256 * 4);
    unsigned short* w_pe2  = (unsigned short*)alloc((size_t)LC * 256 * 256 * 2);
    unsigned short* w_ph1  = (unsigned short*)alloc((size_t)LC * 256 * 256 * 2);
    unsigned short* w_ph2  = (unsigned short*)alloc((size_t)LC * 256 * 256 * 2);
    unsigned short* w_px1  = (unsigned short*)alloc((size_t)LC * 256 * 256 * 2);
    unsigned short* w_ain  = (unsigned short*)alloc((size_t)LC * 768 * 256 * 2);
    unsigned short* w_aout = (unsigned short*)alloc((size_t)LC * 256 * 256 * 2);
    unsigned short* w_ff1  = (unsigned short*)alloc((size_t)LC * 1024 * 256 * 2);
    unsigned short* w_ff2  = (unsigned short*)alloc((size_t)LC * 256 * 1024 * 2);

    // ---- counting sort of edges by col ----
    hipMemsetAsync(cnt, 0, 16384 * 4, stream);
    hist_kernel<<<NEDGEC / 256, 256, 0, stream>>>(ei + NEDGEC, cnt);
    scan16k_kernel<<<1, 256, 0, stream>>>(cnt, ptrw);
    permute_kernel<<<NEDGEC / 256, 256, 0, stream>>>(ei, ei + NEDGEC, ptrw, rowP, colP);

    // ---- convert weights to bf16 ----
    conv_pe1_kernel<<<(LC * 256 * 513 + 255) / 256, 256, 0, stream>>>(pe_w1, w_pe1k, w_last);
    conv_bf16_kernel<<<1536, 256, 0, stream>>>(pe_w2, w_pe2, LC * 256 * 256);
    conv_bf16_kernel<<<1536, 256, 0, stream>>>(ph_w1, w_ph1, LC * 256 * 256);
    conv_bf16_kernel<<<1536, 256, 0, stream>>>(ph_w2, w_ph2, LC * 256 * 256);
    conv_bf16_kernel<<<1536, 256, 0, stream>>>(px_w1, w_px1, LC * 256 * 256);
    conv_bf16_kernel<<<4608, 256, 0, stream>>>(ain_w, w_ain, LC * 768 * 256);
    conv_bf16_kernel<<<1536, 256, 0, stream>>>(aout_w, w_aout, LC * 256 * 256);
    conv_bf16_kernel<<<6144, 256, 0, stream>>>(ff_w1, w_ff1, LC * 1024 * 256);
    conv_bf16_kernel<<<6144, 256, 0, stream>>>(ff_w2, w_ff2, LC * 256 * 1024);

    hipMemcpyAsync(h, x, (size_t)NTOTC * HC * 4, hipMemcpyDeviceToDevice, stream);
    hipMemcpyAsync(cur, pos, (size_t)NTOTC * 3 * 4, hipMemcpyDeviceToDevice, stream);
    conv_bf16_kernel<<<4096, 256, 0, stream>>>(x, h_bf, NTOTC * HC);

    for (int l = 0; l < LC; l++) {
        rel_dist_kernel<<<NEDGEC / 256, 256, 0, stream>>>(cur, rowP, colP, relP, distP);
        hipMemsetAsync(hmsg, 0, (size_t)NTOTC * HC * 4, stream);
        hipMemsetAsync(posupd, 0, (size_t)NTOTC * 3 * 4, stream);

        fused_edge_kernel<<<NEDGEC / 64, 256, 0, stream>>>(
            h_bf, rowP, colP, distP, relP,
            w_pe1k + (size_t)l * 256 * 512, w_last + (size_t)l * 256, pe_b1 + (size_t)l * HC,
            w_pe2 + (size_t)l * 256 * 256, pe_b2 + (size_t)l * HC,
            pe_lg + (size_t)l * HC, pe_lb + (size_t)l * HC,
            w_px1 + (size_t)l * 256 * 256, px_b1 + (size_t)l * HC,
            px_w2 + (size_t)l * HC, px_b2 + l,
            hmsg, posupd);

        // phi_h tail
        pack_add_kernel<<<NTOTC * HC / 256, 256, 0, stream>>>(h, hmsg, hs_bf);
        mgemm_kernel<1, false, false, true><<<dim3(NTOTC / 128, 2), 256, 0, stream>>>(
            hs_bf, w_ph1 + (size_t)l * 256 * 256, ph_b1 + (size_t)l * HC,
            nullptr, nullptr, t_bf, NTOTC, HC, HC);
        node_fused_kernel<true><<<NTOTC / 64, 256, 0, stream>>>(
            t_bf, w_ph2 + (size_t)l * 256 * 256, ph_b2 + (size_t)l * HC,
            ph_lg + (size_t)l * HC, ph_lb + (size_t)l * HC,
            lnh_g + (size_t)l * HC, lnh_b + (size_t)l * HC, h, h_bf);
        cur_update_kernel<<<(NTOTC * 3) / 256, 256, 0, stream>>>(cur, posupd, ps, l);

        // attention
        mgemm_kernel<0, false, false, true><<<dim3(NTOTC / 128, 6), 256, 0, stream>>>(
            h_bf, w_ain + (size_t)l * 768 * 256, ain_b + (size_t)l * 3 * HC,
            nullptr, nullptr, qkv_bf, NTOTC, 3 * HC, HC);
        attn_kernel<<<dim3(NTOTC / 64, NHEADSC), 64, 0, stream>>>(qkv_bf, o_bf);
        node_fused_kernel<false><<<NTOTC / 64, 256, 0, stream>>>(
            o_bf, w_aout + (size_t)l * 256 * 256, aout_b + (size_t)l * HC,
            lna_g + (size_t)l * HC, lna_b + (size_t)l * HC,
            nullptr, nullptr, h, h_bf);

        // feed-forward with residual
        mgemm_kernel<2, false, false, true><<<dim3(NTOTC / 128, 8), 256, 0, stream>>>(
            h_bf, w_ff1 + (size_t)l * 1024 * 256, ff_b1 + (size_t)l * 4 * HC,
            nullptr, nullptr, ff1_bf, NTOTC, 4 * HC, HC);
        mgemm_kernel<0, true, true, true><<<dim3(NTOTC / 128, 2), 256, 0, stream>>>(
            ff1_bf, w_ff2 + (size_t)l * 256 * 1024, ff_b2 + (size_t)l * HC,
            h, h, h_bf, NTOTC, HC, 4 * HC);
    }

    hipMemcpyAsync(d_out, h, (size_t)NTOTC * HC * 4, hipMemcpyDeviceToDevice, stream);
    hipMemcpyAsync((float*)d_out + (size_t)NTOTC * HC, cur, (size_t)NTOTC * 3 * 4,
                   hipMemcpyDeviceToDevice, stream);
}